// Round 15
// baseline (96.518 us; speedup 1.0000x reference)
//
#include <hip/hip_runtime.h>

// Primitive-equations block stepper, gfx950 — R15.
// R14 (32x32 tile, 256 thr) + "no S4 re-read": the ext-D1 phase also computes
// D1(u^2+v^2), D0(u) and captures the (u,v) center per point (same S4 windows,
// same P1q/P0q weights), storing (ku,du,u,v) in d2S. Stencil2 reads only d1S
// (+4 d2S centers, d1c captured from the dl==2 window) — the 40-b128 S4
// re-read is gone. Per-thread b128 ~144 -> ~105. LDS 67.3 KB -> 2 blocks/CU
// (= measured residency anyway).

constexpr int Kz = 8, Hh = 361, Ww = 720;
constexpr int HW = Hh * Ww;              // 259920
constexpr int OFF_DT = Kz * HW * 2;      // 4158720
constexpr int OFF_DQ = OFF_DT + Kz * HW; // 6238080

// ---- pass-1 geometry ----
constexpr int TH = 32, TW = 32;          // outputs per block
constexpr int NTHR = 256;                // 8 thread-cols x 32 rows, 4 waves
constexpr int NCOL = 8;                  // thread columns (4 outputs each)
constexpr int SH = TH + 8, SW4 = TW + 8; // staged region 40 x 40 points
constexpr int EH = TH + 4, EW4 = TW + 4; // ext D1 region 36 x 36
constexpr int SW4P = 41;                 // S4 row stride (1 mod 8)
constexpr int EW4P = 37;                 // d1S/d2S row stride (5 mod 8)
constexpr int PQROW = 40;                // P-table row stride: 5 a-groups x 8
constexpr int GX = (Ww + TW - 1) / TW;   // 23 (last tile partial, guarded)
constexpr int GY = (Hh + TH - 1) / TH;   // 12

__device__ __forceinline__ int clipH(int x) {
  return x < 0 ? 0 : (x > Hh - 1 ? Hh - 1 : x);
}

#define FMA4(acc, s, v)                                                        \
  do {                                                                         \
    acc.x = fmaf((s), (v).x, acc.x);                                           \
    acc.y = fmaf((s), (v).y, acc.y);                                           \
    acc.z = fmaf((s), (v).z, acc.z);                                           \
    acc.w = fmaf((s), (v).w, acc.w);                                           \
  } while (0)

#define ROWV(acc, a, b, c, d, e)                                               \
  do {                                                                         \
    FMA4(acc, wq0, a); FMA4(acc, wq1, b); FMA4(acc, wq2, c);                   \
    FMA4(acc, wq3, d); FMA4(acc, wq4, e);                                      \
  } while (0)

#define ROW5S(acc, q0, q1, q2, q3, q4, a, b, c, d, e)                          \
  acc = fmaf(q0, a, fmaf(q1, b, fmaf(q2, c, fmaf(q3, d, fmaf(q4, e, acc)))))

// ---------------------------------------------------- P0q/P1q tables --------
__global__ __launch_bounds__(256) void pe_tab_pq(
    const float* __restrict__ psi,
    const float* __restrict__ quad,
    float* __restrict__ P0g,
    float* __restrict__ P1g)
{
  int idx = blockIdx.x * 256 + threadIdx.x;   // h*40 + a*8 + b
  if (idx >= Hh * PQROW) return;
  int h = idx / PQROW, o = idx - h * PQROW;
  int a = o >> 3, b = o & 7;
  float v0 = 0.f, v1 = 0.f;
  if (b < 5) {
    #pragma unroll
    for (int kk = 0; kk < 5; ++kk) {
      v0 += psi[kk * (2 * Hh * 25) + h * 25 + a * 5 + b];
      v1 += psi[kk * (2 * Hh * 25) + Hh * 25 + h * 25 + a * 5 + b];
    }
    float qv = quad[clipH(h + a - 2)];
    v0 *= qv; v1 *= qv;
  }
  P0g[idx] = v0;
  P1g[idx] = v1;
}

// ---------------------------------------------------------------- pass 1 ----
__global__ __launch_bounds__(NTHR) void pe_pass1(
    const float2* __restrict__ uv,
    const float*  __restrict__ Tg,
    const float*  __restrict__ qg,
    const float*  __restrict__ P0g,
    const float*  __restrict__ P1g,
    const float*  __restrict__ f_cor,
    const float*  __restrict__ delta_p,
    float* __restrict__ out,
    float2* __restrict__ ws)
{
  __shared__ float4 S4[SH][SW4P];       // (u,v,T,q), 25.6 KB
  __shared__ float4 d1S[EH][EW4P];      // (d1u,d1v,d1T,d1q), 20.8 KB
  __shared__ float4 d2S[EH][EW4P];      // (D1ke, D0u, u_c, v_c), 20.8 KB

  const int tid = threadIdx.x;
  const int tx = tid % NCOL;            // thread col (owns 4 outputs)
  const int ty = tid / NCOL;            // thread row 0..31
  const int w0 = blockIdx.x * TW;
  const int h0 = blockIdx.y * TH;
  const int k  = blockIdx.z;

  // ---- stage (u,v,T,q) as float4 with +-4 halo (clip lat, wrap lon) ----
  for (int idx = tid; idx < SH * SW4; idx += NTHR) {
    int rr = idx / SW4, cc = idx - rr * SW4;
    int pr = clipH(h0 + rr - 4);
    int pc = w0 + cc - 4;
    pc = pc < 0 ? pc + Ww : (pc >= Ww ? pc - Ww : pc);
    int g = (k * Hh + pr) * Ww + pc;
    float2 uvv = uv[g];
    S4[rr][cc] = make_float4(uvv.x, uvv.y, Tg[g], qg[g]);
  }
  __syncthreads();

  // ---- ext-D1 + fused ke-D1 / u-D0 / center capture ----
  for (int idx = tid; idx < EH * (EW4 / 4); idx += NTHR) {
    int ee = idx % EH;                  // row fastest -> wave spans rows
    int gc = idx / EH;                  // 0..8
    int cb = gc * 4;
    int p = clipH(h0 + ee - 2);
    const float* Pr  = P1g + p * PQROW;
    const float* Pr0 = P0g + p * PQROW;
    float4 a0 = {0,0,0,0}, a1 = {0,0,0,0}, a2 = {0,0,0,0}, a3 = {0,0,0,0};
    float ku0 = 0, ku1 = 0, ku2 = 0, ku3 = 0;   // D1(u^2+v^2)
    float du0 = 0, du1 = 0, du2 = 0, du3 = 0;   // D0(u)
    float2 c0, c1, c2, c3;                      // (u,v) centers
    #pragma unroll
    for (int dl = 0; dl < 5; ++dl) {
      int sp = clipH(p + dl - 2);
      int rr = sp - h0 + 4;
      const float4* row = &S4[rr][cb];
      float4 g0 = row[0], g1 = row[1], g2 = row[2], g3 = row[3];
      float4 g4 = row[4], g5 = row[5], g6 = row[6], g7 = row[7];
      float ka0 = fmaf(g0.y, g0.y, g0.x * g0.x);
      float ka1 = fmaf(g1.y, g1.y, g1.x * g1.x);
      float ka2 = fmaf(g2.y, g2.y, g2.x * g2.x);
      float ka3 = fmaf(g3.y, g3.y, g3.x * g3.x);
      float ka4 = fmaf(g4.y, g4.y, g4.x * g4.x);
      float ka5 = fmaf(g5.y, g5.y, g5.x * g5.x);
      float ka6 = fmaf(g6.y, g6.y, g6.x * g6.x);
      float ka7 = fmaf(g7.y, g7.y, g7.x * g7.x);
      float4 wA = *(const float4*)(Pr + dl * 8);
      float wq0 = wA.x, wq1 = wA.y, wq2 = wA.z, wq3 = wA.w;
      float wq4 = Pr[dl * 8 + 4];
      float4 w0A = *(const float4*)(Pr0 + dl * 8);
      float p0 = w0A.x, p1 = w0A.y, p2 = w0A.z, p3 = w0A.w;
      float p4 = Pr0[dl * 8 + 4];
      ROWV(a0, g0, g1, g2, g3, g4);
      ROWV(a1, g1, g2, g3, g4, g5);
      ROWV(a2, g2, g3, g4, g5, g6);
      ROWV(a3, g3, g4, g5, g6, g7);
      ROW5S(ku0, wq0, wq1, wq2, wq3, wq4, ka0, ka1, ka2, ka3, ka4);
      ROW5S(ku1, wq0, wq1, wq2, wq3, wq4, ka1, ka2, ka3, ka4, ka5);
      ROW5S(ku2, wq0, wq1, wq2, wq3, wq4, ka2, ka3, ka4, ka5, ka6);
      ROW5S(ku3, wq0, wq1, wq2, wq3, wq4, ka3, ka4, ka5, ka6, ka7);
      ROW5S(du0, p0, p1, p2, p3, p4, g0.x, g1.x, g2.x, g3.x, g4.x);
      ROW5S(du1, p0, p1, p2, p3, p4, g1.x, g2.x, g3.x, g4.x, g5.x);
      ROW5S(du2, p0, p1, p2, p3, p4, g2.x, g3.x, g4.x, g5.x, g6.x);
      ROW5S(du3, p0, p1, p2, p3, p4, g3.x, g4.x, g5.x, g6.x, g7.x);
      if (dl == 2) {
        c0 = make_float2(g2.x, g2.y);
        c1 = make_float2(g3.x, g3.y);
        c2 = make_float2(g4.x, g4.y);
        c3 = make_float2(g5.x, g5.y);
      }
    }
    d1S[ee][cb + 0] = a0; d1S[ee][cb + 1] = a1;
    d1S[ee][cb + 2] = a2; d1S[ee][cb + 3] = a3;
    d2S[ee][cb + 0] = make_float4(ku0, du0, c0.x, c0.y);
    d2S[ee][cb + 1] = make_float4(ku1, du1, c1.x, c1.y);
    d2S[ee][cb + 2] = make_float4(ku2, du2, c2.x, c2.y);
    d2S[ee][cb + 3] = make_float4(ku3, du3, c3.x, c3.y);
  }
  __syncthreads();

  const int h = h0 + ty;
  const int hc = h < Hh ? h : (Hh - 1);
  const int wbase = w0 + tx * 4;
  const float f = f_cor[hc];
  const float invR = (float)(1.0 / 6371000.0);
  const float halfInvR = 0.5f * invR;
  const float cL = 200000.0f * invR * invR;
  const float* Pr1 = P1g + hc * PQROW;

  // ---- second stencil: laplacians from d1S only ----
  float4 lp0 = {0,0,0,0}, lp1 = {0,0,0,0}, lp2 = {0,0,0,0}, lp3 = {0,0,0,0};
  float4 d1c0, d1c1, d1c2, d1c3;        // centers captured at dl==2
  #pragma unroll
  for (int dl = 0; dl < 5; ++dl) {
    int sp = clipH(hc + dl - 2);
    int er = sp - h0 + 2;               // d1S row
    float4 wA = *(const float4*)(Pr1 + dl * 8);
    float wq0 = wA.x, wq1 = wA.y, wq2 = wA.z, wq3 = wA.w;
    float wq4 = Pr1[dl * 8 + 4];
    const float4* row = &d1S[er][tx * 4];
    float4 g0 = row[0], g1 = row[1], g2 = row[2], g3 = row[3];
    float4 g4 = row[4], g5 = row[5], g6 = row[6], g7 = row[7];
    ROWV(lp0, g0, g1, g2, g3, g4);
    ROWV(lp1, g1, g2, g3, g4, g5);
    ROWV(lp2, g2, g3, g4, g5, g6);
    ROWV(lp3, g3, g4, g5, g6, g7);
    if (dl == 2) { d1c0 = g2; d1c1 = g3; d1c2 = g4; d1c3 = g5; }
  }

  if (h < Hh && wbase < Ww) {
    const float dpk = delta_p[k];
    float4 duvA, duvB, dTv, dqv, wsA, wsB;
    {
      float4 kd = d2S[ty + 2][tx * 4 + 2];
      float coef1 = fmaf(kd.y, invR, -f);
      duvA.x = fmaf(-coef1, kd.w, cL * lp0.x);
      duvA.y = fmaf(coef1, kd.z, -halfInvR * kd.x) + cL * lp0.y;
      dTv.x = -(invR * d1c0.z) * kd.w + cL * lp0.z;
      dqv.x = fmaf(-(invR * d1c0.w), kd.w, cL * lp0.w);
      wsA.x = invR * d1c0.y * dpk; wsA.y = d1c0.z;
    }
    {
      float4 kd = d2S[ty + 2][tx * 4 + 3];
      float coef1 = fmaf(kd.y, invR, -f);
      duvA.z = fmaf(-coef1, kd.w, cL * lp1.x);
      duvA.w = fmaf(coef1, kd.z, -halfInvR * kd.x) + cL * lp1.y;
      dTv.y = -(invR * d1c1.z) * kd.w + cL * lp1.z;
      dqv.y = fmaf(-(invR * d1c1.w), kd.w, cL * lp1.w);
      wsA.z = invR * d1c1.y * dpk; wsA.w = d1c1.z;
    }
    {
      float4 kd = d2S[ty + 2][tx * 4 + 4];
      float coef1 = fmaf(kd.y, invR, -f);
      duvB.x = fmaf(-coef1, kd.w, cL * lp2.x);
      duvB.y = fmaf(coef1, kd.z, -halfInvR * kd.x) + cL * lp2.y;
      dTv.z = -(invR * d1c2.z) * kd.w + cL * lp2.z;
      dqv.z = fmaf(-(invR * d1c2.w), kd.w, cL * lp2.w);
      wsB.x = invR * d1c2.y * dpk; wsB.y = d1c2.z;
    }
    {
      float4 kd = d2S[ty + 2][tx * 4 + 5];
      float coef1 = fmaf(kd.y, invR, -f);
      duvB.z = fmaf(-coef1, kd.w, cL * lp3.x);
      duvB.w = fmaf(coef1, kd.z, -halfInvR * kd.x) + cL * lp3.y;
      dTv.w = -(invR * d1c3.z) * kd.w + cL * lp3.z;
      dqv.w = fmaf(-(invR * d1c3.w), kd.w, cL * lp3.w);
      wsB.z = invR * d1c3.y * dpk; wsB.w = d1c3.z;
    }
    const int gidx = (k * Hh + h) * Ww + wbase;
    float4* o4 = (float4*)out;
    o4[gidx >> 1] = duvA;
    o4[(gidx >> 1) + 1] = duvB;
    *(float4*)&out[OFF_DT + gidx] = dTv;
    *(float4*)&out[OFF_DQ + gidx] = dqv;
    float4* w4 = (float4*)ws;
    w4[gidx >> 1] = wsA;
    w4[(gidx >> 1) + 1] = wsB;
  }
}

// ---------------------------------------------------------------- pass 2 ----
__global__ __launch_bounds__(256) void pe_pass2(
    const float* __restrict__ Tg,
    const float* __restrict__ p_levels,
    const float2* __restrict__ ws,
    float* __restrict__ out)
{
  int i4 = blockIdx.x * 256 + threadIdx.x;   // quad index (4 points/thread)
  if (i4 >= HW / 4) return;
  const float invR = (float)(1.0 / 6371000.0);
  const float RCP = (float)(287.0 / 1004.0);

  float pl[Kz];
  #pragma unroll
  for (int k = 0; k < Kz; ++k) pl[k] = p_levels[k];

  const float4* T4 = (const float4*)Tg;
  const float4* ws4 = (const float4*)ws;
  float4* o4 = (float4*)out;
  float4* dT4 = (float4*)(out + OFF_DT);

  float4 cum = {0,0,0,0}, sumT = {0,0,0,0};
  float4 Tm = {0,0,0,0}, Tc = T4[i4];

  #pragma unroll
  for (int k = 0; k < Kz; ++k) {
    float4 Tp = (k < Kz - 1) ? T4[(k + 1) * (HW / 4) + i4] : make_float4(0,0,0,0);
    float4 wa = ws4[k * (HW / 2) + 2 * i4];
    float4 wb = ws4[k * (HW / 2) + 2 * i4 + 1];
    float om0 = fmaf(0.5f, wa.x, cum.x); cum.x += wa.x;
    float om1 = fmaf(0.5f, wa.z, cum.y); cum.y += wa.z;
    float om2 = fmaf(0.5f, wb.x, cum.z); cum.z += wb.x;
    float om3 = fmaf(0.5f, wb.z, cum.w); cum.w += wb.z;

    float4 dTdp;
    if (k == 0) {
      float idp = 1.f / (pl[1] - pl[0]);
      dTdp.x = (Tp.x - Tc.x) * idp; dTdp.y = (Tp.y - Tc.y) * idp;
      dTdp.z = (Tp.z - Tc.z) * idp; dTdp.w = (Tp.w - Tc.w) * idp;
    } else if (k == Kz - 1) {
      float idp = 1.f / (pl[Kz - 1] - pl[Kz - 2]);
      dTdp.x = (Tc.x - Tm.x) * idp; dTdp.y = (Tc.y - Tm.y) * idp;
      dTdp.z = (Tc.z - Tm.z) * idp; dTdp.w = (Tc.w - Tm.w) * idp;
    } else {
      float idp = 1.f / (pl[k + 1] - pl[k - 1]);
      dTdp.x = (Tp.x - Tm.x) * idp; dTdp.y = (Tp.y - Tm.y) * idp;
      dTdp.z = (Tp.z - Tm.z) * idp; dTdp.w = (Tp.w - Tm.w) * idp;
    }
    float iplk = RCP / pl[k];
    float4 dt = dT4[k * (HW / 4) + i4];
    dt.x += om0 * fmaf(iplk, Tc.x, -dTdp.x);
    dt.y += om1 * fmaf(iplk, Tc.y, -dTdp.y);
    dt.z += om2 * fmaf(iplk, Tc.z, -dTdp.z);
    dt.w += om3 * fmaf(iplk, Tc.w, -dTdp.w);
    dT4[k * (HW / 4) + i4] = dt;

    float4 oa = o4[k * (HW / 2) + 2 * i4];
    float4 ob = o4[k * (HW / 2) + 2 * i4 + 1];
    oa.y += sumT.x; oa.w += sumT.y;
    ob.y += sumT.z; ob.w += sumT.w;
    o4[k * (HW / 2) + 2 * i4] = oa;
    o4[k * (HW / 2) + 2 * i4 + 1] = ob;

    if (k < Kz - 1) {
      float c = -287.0f * logf(pl[k] / pl[k + 1]) * invR;
      sumT.x = fmaf(c, wa.y, sumT.x);
      sumT.y = fmaf(c, wa.w, sumT.y);
      sumT.z = fmaf(c, wb.y, sumT.z);
      sumT.w = fmaf(c, wb.w, sumT.w);
    }
    Tm = Tc; Tc = Tp;
  }
}

// ------------------------------------------------- fallback fused kernel ----
constexpr int FTH = 16, FTW = 16;
constexpr int FSH = FTH + 8, FSW = FTW + 8;
constexpr int FEH = FTH + 4, FEW = FTW + 4;
constexpr int FSWp = FSW + 1, FEWp = FEW + 1;

__global__ __launch_bounds__(256) void pe_step(
    const float2* __restrict__ uv,
    const float*  __restrict__ Tg,
    const float*  __restrict__ qg,
    const float*  __restrict__ psi,
    const float*  __restrict__ quad,
    const float*  __restrict__ f_cor,
    const float*  __restrict__ p_levels,
    const float*  __restrict__ delta_p,
    float* __restrict__ out)
{
  __shared__ float uS[FSH][FSWp], vS[FSH][FSWp], TS[FSH][FSWp], qS[FSH][FSWp];
  __shared__ float keS[FEH][FEWp];
  __shared__ float d1uS[FEH][FEWp], d1vS[FEH][FEWp], d1TS[FEH][FEWp], d1qS[FEH][FEWp];
  __shared__ float P1L[FEH][25];
  __shared__ float P0L[FTH][25];
  __shared__ float quadA[FSH];
  __shared__ float pl[8], dps[8];

  const int tid = threadIdx.x;
  const int tx = tid & (FTW - 1);
  const int ty = tid >> 4;
  const int w0 = blockIdx.x * FTW;
  const int h0 = blockIdx.y * FTH;

  if (tid < FSH) quadA[tid] = quad[clipH(h0 + tid - 4)];
  if (tid < 8) { pl[tid] = p_levels[tid]; dps[tid] = delta_p[tid]; }
  for (int idx = tid; idx < FEH * 25; idx += 256) {
    int ee = idx / 25, t = idx - ee * 25;
    int p = clipH(h0 + ee - 2);
    float s = 0.f;
    #pragma unroll
    for (int kk = 0; kk < 5; ++kk)
      s += psi[kk * (2 * Hh * 25) + Hh * 25 + p * 25 + t];
    P1L[ee][t] = s;
  }
  for (int idx = tid; idx < FTH * 25; idx += 256) {
    int r = idx / 25, t = idx - r * 25;
    int p = clipH(h0 + r);
    float s = 0.f;
    #pragma unroll
    for (int kk = 0; kk < 5; ++kk)
      s += psi[kk * (2 * Hh * 25) + p * 25 + t];
    P0L[r][t] = s;
  }
  __syncthreads();

  const int h = h0 + ty;
  const bool act = h < Hh;
  const int hc = act ? h : (Hh - 1);
  const int w = w0 + tx;
  const float f = f_cor[hc];
  const float invR = (float)(1.0 / 6371000.0);
  const float cL = 200000.0f * invR * invR;
  const float RCP = (float)(287.0 / 1004.0);

  float cum = 0.f;
  float sumT = 0.f;

  #pragma unroll 1
  for (int k = 0; k < Kz; ++k) {
    __syncthreads();
    for (int idx = tid; idx < FSH * FSW; idx += 256) {
      int rr = idx / FSW, cc = idx - rr * FSW;
      int pr = clipH(h0 + rr - 4);
      int pc = w0 + cc - 4;
      pc = pc < 0 ? pc + Ww : (pc >= Ww ? pc - Ww : pc);
      int g = (k * Hh + pr) * Ww + pc;
      float2 uvv = uv[g];
      uS[rr][cc] = uvv.x; vS[rr][cc] = uvv.y;
      TS[rr][cc] = Tg[g]; qS[rr][cc] = qg[g];
    }
    __syncthreads();
    for (int idx = tid; idx < FEH * FEW; idx += 256) {
      int ee = idx / FEW, ec = idx - ee * FEW;
      float su = uS[ee + 2][ec + 2], sv = vS[ee + 2][ec + 2];
      keS[ee][ec] = 0.5f * (su * su + sv * sv);
    }
    for (int idx = tid; idx < FEH * FEW; idx += 256) {
      int ee = idx / FEW, ec = idx - ee * FEW;
      int p = clipH(h0 + ee - 2);
      float au = 0.f, av = 0.f, aT = 0.f, aq = 0.f;
      #pragma unroll
      for (int dl = 0; dl < 5; ++dl) {
        int sp = clipH(p + dl - 2);
        int rr = sp - h0 + 4;
        float qv = quadA[rr];
        float ru = 0.f, rv = 0.f, rT = 0.f, rq = 0.f;
        #pragma unroll
        for (int dw = 0; dw < 5; ++dw) {
          float wgt = P1L[ee][dl * 5 + dw];
          ru = fmaf(wgt, uS[rr][ec + dw], ru);
          rv = fmaf(wgt, vS[rr][ec + dw], rv);
          rT = fmaf(wgt, TS[rr][ec + dw], rT);
          rq = fmaf(wgt, qS[rr][ec + dw], rq);
        }
        au = fmaf(qv, ru, au); av = fmaf(qv, rv, av);
        aT = fmaf(qv, rT, aT); aq = fmaf(qv, rq, aq);
      }
      d1uS[ee][ec] = au; d1vS[ee][ec] = av;
      d1TS[ee][ec] = aT; d1qS[ee][ec] = aq;
    }
    __syncthreads();

    float d0u = 0.f, d1ke = 0.f;
    #pragma unroll
    for (int dl = 0; dl < 5; ++dl) {
      int sp = clipH(hc + dl - 2);
      int rr = sp - h0 + 4;
      int er = sp - h0 + 2;
      float qv = quadA[rr];
      float r0 = 0.f, rk = 0.f;
      #pragma unroll
      for (int dw = 0; dw < 5; ++dw) {
        r0 = fmaf(P0L[ty][dl * 5 + dw], uS[rr][tx + 2 + dw], r0);
        rk = fmaf(P1L[ty + 2][dl * 5 + dw], keS[er][tx + dw], rk);
      }
      d0u = fmaf(qv, r0, d0u);
      d1ke = fmaf(qv, rk, d1ke);
    }

    float lapu = 0.f, lapv = 0.f, lapT = 0.f, lapq = 0.f;
    #pragma unroll
    for (int dl = 0; dl < 5; ++dl) {
      int sp = clipH(hc + dl - 2);
      int er = sp - h0 + 2;
      float qv = quadA[er + 2];
      float ru = 0.f, rv = 0.f, rT = 0.f, rq = 0.f;
      #pragma unroll
      for (int dw = 0; dw < 5; ++dw) {
        float wgt = P1L[ty + 2][dl * 5 + dw];
        ru = fmaf(wgt, d1uS[er][tx + dw], ru);
        rv = fmaf(wgt, d1vS[er][tx + dw], rv);
        rT = fmaf(wgt, d1TS[er][tx + dw], rT);
        rq = fmaf(wgt, d1qS[er][tx + dw], rq);
      }
      lapu = fmaf(qv, ru, lapu); lapv = fmaf(qv, rv, lapv);
      lapT = fmaf(qv, rT, lapT); lapq = fmaf(qv, rq, lapq);
    }

    float d1T_c = d1TS[ty + 2][tx + 2];
    float d1v_c = d1vS[ty + 2][tx + 2];
    float d1q_c = d1qS[ty + 2][tx + 2];
    float uc = uS[ty + 4][tx + 4], vc = vS[ty + 4][tx + 4];
    float Tc = TS[ty + 4][tx + 4];

    float coef1 = fmaf(d0u, invR, -f);
    float duv0 = fmaf(-coef1, vc, cL * lapu);
    float yv1 = fmaf(-invR, d1ke, sumT);
    float duv1 = fmaf(coef1, uc, yv1) + cL * lapv;

    float div = invR * d1v_c;
    float dpk = dps[k];
    float omega = fmaf(0.5f * div, dpk, cum);
    cum = fmaf(div, dpk, cum);

    int gidx = (k * Hh + hc) * Ww + w;
    float dTdp;
    if (k == 0) {
      float Tp = Tg[gidx + HW];
      dTdp = (Tp - Tc) / (pl[1] - pl[0]);
    } else if (k == Kz - 1) {
      float Tm = Tg[gidx - HW];
      dTdp = (Tc - Tm) / (pl[Kz - 1] - pl[Kz - 2]);
    } else {
      float Tp = Tg[gidx + HW];
      float Tm = Tg[gidx - HW];
      dTdp = (Tp - Tm) / (pl[k + 1] - pl[k - 1]);
    }
    float adv = -(invR * d1T_c) * vc;
    float dT = adv + omega * ((RCP * Tc) / pl[k] - dTdp) + cL * lapT;
    float dq = fmaf(-(invR * d1q_c), vc, cL * lapq);

    if (act) {
      ((float2*)out)[(k * Hh + h) * Ww + w] = make_float2(duv0, duv1);
      out[OFF_DT + gidx] = dT;
      out[OFF_DQ + gidx] = dq;
    }

    if (k < Kz - 1) {
      float lpr = logf(pl[k] / pl[k + 1]);
      float wTk = (float)(-287.0 * (double)lpr / 6371000.0);
      sumT = fmaf(wTk, d1T_c, sumT);
    }
  }
}

extern "C" void kernel_launch(void* const* d_in, const int* in_sizes, int n_in,
                              void* d_out, int out_size, void* d_ws, size_t ws_size,
                              hipStream_t stream) {
  (void)in_sizes; (void)n_in; (void)out_size;
  const float2* uv   = (const float2*)d_in[0];
  const float*  T    = (const float*) d_in[1];
  const float*  q    = (const float*) d_in[2];
  const float*  psi  = (const float*) d_in[3];
  const float*  quad = (const float*) d_in[4];
  const float*  fc   = (const float*) d_in[5];
  const float*  pl   = (const float*) d_in[6];
  const float*  dp   = (const float*) d_in[7];

  const size_t ws_div_floats = (size_t)2 * Kz * HW;        // K*HW float2
  const size_t pq_floats = (size_t)Hh * PQROW;             // 14440
  const size_t ws_need = (ws_div_floats + 2 * pq_floats) * sizeof(float);
  if (ws_size >= ws_need) {
    float* wsF = (float*)d_ws;
    float* P0g = wsF + ws_div_floats;
    float* P1g = P0g + pq_floats;

    dim3 gt1((Hh * PQROW + 255) / 256);                    // 57 blocks
    hipLaunchKernelGGL(pe_tab_pq, gt1, dim3(256), 0, stream, psi, quad, P0g, P1g);

    dim3 g1(GX, GY, Kz);                                   // 23 x 12 x 8
    hipLaunchKernelGGL(pe_pass1, g1, dim3(NTHR), 0, stream,
                       uv, T, q, P0g, P1g, fc, dp, (float*)d_out, (float2*)d_ws);

    dim3 g2((HW / 4 + 255) / 256);
    hipLaunchKernelGGL(pe_pass2, g2, dim3(256), 0, stream,
                       T, pl, (const float2*)d_ws, (float*)d_out);
  } else {
    dim3 grid(Ww / FTW, (Hh + FTH - 1) / FTH);
    hipLaunchKernelGGL(pe_step, grid, dim3(256), 0, stream,
                       uv, T, q, psi, quad, fc, pl, dp, (float*)d_out);
  }
}

// Round 16
// 67.888 us; speedup vs baseline: 1.4217x; 1.4217x over previous
//
#include <hip/hip_runtime.h>

// Primitive-equations block stepper, gfx950 — R16 (= R14, best config).
// Two-stage 5x5 stencils, 32x32 tile, 256 thr (8 cols x 4 outputs), LDS 47.6
// KB. Established optimum: R13 (8-wide, 53KB) and R15 (fused d2S, 69KB) both
// regressed via occupancy/VALU cost; R14 measured 52 us pass1 / 68.1 total.

constexpr int Kz = 8, Hh = 361, Ww = 720;
constexpr int HW = Hh * Ww;              // 259920
constexpr int OFF_DT = Kz * HW * 2;      // 4158720
constexpr int OFF_DQ = OFF_DT + Kz * HW; // 6238080

// ---- pass-1 geometry ----
constexpr int TH = 32, TW = 32;          // outputs per block
constexpr int NTHR = 256;                // 8 thread-cols x 32 rows, 4 waves
constexpr int NCOL = 8;                  // thread columns (4 outputs each)
constexpr int SH = TH + 8, SW4 = TW + 8; // staged region 40 x 40 points
constexpr int EH = TH + 4, EW4 = TW + 4; // ext D1 region 36 x 36
constexpr int SW4P = 41;                 // S4 row stride (1 mod 8)
constexpr int EW4P = 37;                 // d1S row stride (5 mod 8)
constexpr int PQROW = 40;                // P-table row stride: 5 a-groups x 8
constexpr int GX = (Ww + TW - 1) / TW;   // 23 (last tile partial, guarded)
constexpr int GY = (Hh + TH - 1) / TH;   // 12

__device__ __forceinline__ int clipH(int x) {
  return x < 0 ? 0 : (x > Hh - 1 ? Hh - 1 : x);
}

#define FMA4(acc, s, v)                                                        \
  do {                                                                         \
    acc.x = fmaf((s), (v).x, acc.x);                                           \
    acc.y = fmaf((s), (v).y, acc.y);                                           \
    acc.z = fmaf((s), (v).z, acc.z);                                           \
    acc.w = fmaf((s), (v).w, acc.w);                                           \
  } while (0)

#define ROWV(acc, a, b, c, d, e)                                               \
  do {                                                                         \
    FMA4(acc, wq0, a); FMA4(acc, wq1, b); FMA4(acc, wq2, c);                   \
    FMA4(acc, wq3, d); FMA4(acc, wq4, e);                                      \
  } while (0)

#define ROW5S(acc, q0, q1, q2, q3, q4, a, b, c, d, e)                          \
  acc = fmaf(q0, a, fmaf(q1, b, fmaf(q2, c, fmaf(q3, d, fmaf(q4, e, acc)))))

// ---------------------------------------------------- P0q/P1q tables --------
__global__ __launch_bounds__(256) void pe_tab_pq(
    const float* __restrict__ psi,
    const float* __restrict__ quad,
    float* __restrict__ P0g,
    float* __restrict__ P1g)
{
  int idx = blockIdx.x * 256 + threadIdx.x;   // h*40 + a*8 + b
  if (idx >= Hh * PQROW) return;
  int h = idx / PQROW, o = idx - h * PQROW;
  int a = o >> 3, b = o & 7;
  float v0 = 0.f, v1 = 0.f;
  if (b < 5) {
    #pragma unroll
    for (int kk = 0; kk < 5; ++kk) {
      v0 += psi[kk * (2 * Hh * 25) + h * 25 + a * 5 + b];
      v1 += psi[kk * (2 * Hh * 25) + Hh * 25 + h * 25 + a * 5 + b];
    }
    float qv = quad[clipH(h + a - 2)];
    v0 *= qv; v1 *= qv;
  }
  P0g[idx] = v0;
  P1g[idx] = v1;
}

// ---------------------------------------------------------------- pass 1 ----
__global__ __launch_bounds__(NTHR) void pe_pass1(
    const float2* __restrict__ uv,
    const float*  __restrict__ Tg,
    const float*  __restrict__ qg,
    const float*  __restrict__ P0g,
    const float*  __restrict__ P1g,
    const float*  __restrict__ f_cor,
    const float*  __restrict__ delta_p,
    float* __restrict__ out,
    float2* __restrict__ ws)
{
  __shared__ float4 S4[SH][SW4P];       // (u,v,T,q), 26.2 KB
  __shared__ float4 d1S[EH][EW4P];      // (d1u,d1v,d1T,d1q), 21.3 KB

  const int tid = threadIdx.x;
  const int tx = tid % NCOL;            // thread col (owns 4 outputs)
  const int ty = tid / NCOL;            // thread row 0..31
  const int w0 = blockIdx.x * TW;
  const int h0 = blockIdx.y * TH;
  const int k  = blockIdx.z;

  // ---- stage (u,v,T,q) as float4 with +-4 halo (clip lat, wrap lon) ----
  for (int idx = tid; idx < SH * SW4; idx += NTHR) {
    int rr = idx / SW4, cc = idx - rr * SW4;
    int pr = clipH(h0 + rr - 4);
    int pc = w0 + cc - 4;
    pc = pc < 0 ? pc + Ww : (pc >= Ww ? pc - Ww : pc);
    int g = (k * Hh + pr) * Ww + pc;
    float2 uvv = uv[g];
    S4[rr][cc] = make_float4(uvv.x, uvv.y, Tg[g], qg[g]);
  }
  __syncthreads();

  // ---- extended D1 of (u,v,T,q): 36 x 9 groups, ee-fastest lane map ----
  for (int idx = tid; idx < EH * (EW4 / 4); idx += NTHR) {
    int ee = idx % EH;                  // row fastest -> wave spans rows
    int gc = idx / EH;                  // 0..8
    int cb = gc * 4;
    int p = clipH(h0 + ee - 2);
    const float* Pr = P1g + p * PQROW;
    float4 a0 = {0,0,0,0}, a1 = {0,0,0,0}, a2 = {0,0,0,0}, a3 = {0,0,0,0};
    #pragma unroll
    for (int dl = 0; dl < 5; ++dl) {
      int sp = clipH(p + dl - 2);
      int rr = sp - h0 + 4;
      const float4* row = &S4[rr][cb];
      float4 g0 = row[0], g1 = row[1], g2 = row[2], g3 = row[3];
      float4 g4 = row[4], g5 = row[5], g6 = row[6], g7 = row[7];
      float4 wA = *(const float4*)(Pr + dl * 8);
      float wq0 = wA.x, wq1 = wA.y, wq2 = wA.z, wq3 = wA.w;
      float wq4 = Pr[dl * 8 + 4];
      ROWV(a0, g0, g1, g2, g3, g4);
      ROWV(a1, g1, g2, g3, g4, g5);
      ROWV(a2, g2, g3, g4, g5, g6);
      ROWV(a3, g3, g4, g5, g6, g7);
    }
    d1S[ee][cb + 0] = a0; d1S[ee][cb + 1] = a1;
    d1S[ee][cb + 2] = a2; d1S[ee][cb + 3] = a3;
  }
  __syncthreads();

  const int h = h0 + ty;
  const int hc = h < Hh ? h : (Hh - 1);
  const int wbase = w0 + tx * 4;
  const float f = f_cor[hc];
  const float invR = (float)(1.0 / 6371000.0);
  const float halfInvR = 0.5f * invR;
  const float cL = 200000.0f * invR * invR;
  const float* Pr1 = P1g + hc * PQROW;
  const float* Pr0 = P0g + hc * PQROW;

  // ---- second stencil: laplacians (d1S), D0(u) & D1(u^2+v^2) (S4) ----
  float4 lp0 = {0,0,0,0}, lp1 = {0,0,0,0}, lp2 = {0,0,0,0}, lp3 = {0,0,0,0};
  float du0 = 0.f, du1 = 0.f, du2 = 0.f, du3 = 0.f;   // D0(u)
  float dk0 = 0.f, dk1 = 0.f, dk2 = 0.f, dk3 = 0.f;   // D1(u^2+v^2)
  #pragma unroll
  for (int dl = 0; dl < 5; ++dl) {
    int sp = clipH(hc + dl - 2);
    int er = sp - h0 + 2;               // d1S row
    int rr = er + 2;                    // S4 row
    float4 wA = *(const float4*)(Pr1 + dl * 8);
    float wq0 = wA.x, wq1 = wA.y, wq2 = wA.z, wq3 = wA.w;
    float wq4 = Pr1[dl * 8 + 4];
    {
      const float4* row = &d1S[er][tx * 4];
      float4 g0 = row[0], g1 = row[1], g2 = row[2], g3 = row[3];
      float4 g4 = row[4], g5 = row[5], g6 = row[6], g7 = row[7];
      ROWV(lp0, g0, g1, g2, g3, g4);
      ROWV(lp1, g1, g2, g3, g4, g5);
      ROWV(lp2, g2, g3, g4, g5, g6);
      ROWV(lp3, g3, g4, g5, g6, g7);
    }
    {
      const float4* srow = &S4[rr][tx * 4 + 2];
      float4 s0 = srow[0], s1 = srow[1], s2 = srow[2], s3 = srow[3];
      float4 s4 = srow[4], s5 = srow[5], s6 = srow[6], s7 = srow[7];
      float k0 = fmaf(s0.y, s0.y, s0.x * s0.x);
      float k1 = fmaf(s1.y, s1.y, s1.x * s1.x);
      float k2 = fmaf(s2.y, s2.y, s2.x * s2.x);
      float k3 = fmaf(s3.y, s3.y, s3.x * s3.x);
      float k4 = fmaf(s4.y, s4.y, s4.x * s4.x);
      float k5 = fmaf(s5.y, s5.y, s5.x * s5.x);
      float k6 = fmaf(s6.y, s6.y, s6.x * s6.x);
      float k7 = fmaf(s7.y, s7.y, s7.x * s7.x);
      ROW5S(dk0, wq0, wq1, wq2, wq3, wq4, k0, k1, k2, k3, k4);
      ROW5S(dk1, wq0, wq1, wq2, wq3, wq4, k1, k2, k3, k4, k5);
      ROW5S(dk2, wq0, wq1, wq2, wq3, wq4, k2, k3, k4, k5, k6);
      ROW5S(dk3, wq0, wq1, wq2, wq3, wq4, k3, k4, k5, k6, k7);
      float4 w0A = *(const float4*)(Pr0 + dl * 8);
      float q0 = w0A.x, q1 = w0A.y, q2 = w0A.z, q3 = w0A.w;
      float q4 = Pr0[dl * 8 + 4];
      ROW5S(du0, q0, q1, q2, q3, q4, s0.x, s1.x, s2.x, s3.x, s4.x);
      ROW5S(du1, q0, q1, q2, q3, q4, s1.x, s2.x, s3.x, s4.x, s5.x);
      ROW5S(du2, q0, q1, q2, q3, q4, s2.x, s3.x, s4.x, s5.x, s6.x);
      ROW5S(du3, q0, q1, q2, q3, q4, s3.x, s4.x, s5.x, s6.x, s7.x);
    }
  }

  if (h < Hh && wbase < Ww) {
    const float dpk = delta_p[k];
    float4 duvA, duvB, dTv, dqv, wsA, wsB;
    {
      float4 d1c = d1S[ty + 2][tx * 4 + 2];
      float4 ctr = S4[ty + 4][tx * 4 + 4];
      float coef1 = fmaf(du0, invR, -f);
      duvA.x = fmaf(-coef1, ctr.y, cL * lp0.x);
      duvA.y = fmaf(coef1, ctr.x, -halfInvR * dk0) + cL * lp0.y;
      dTv.x = -(invR * d1c.z) * ctr.y + cL * lp0.z;
      dqv.x = fmaf(-(invR * d1c.w), ctr.y, cL * lp0.w);
      wsA.x = invR * d1c.y * dpk; wsA.y = d1c.z;
    }
    {
      float4 d1c = d1S[ty + 2][tx * 4 + 3];
      float4 ctr = S4[ty + 4][tx * 4 + 5];
      float coef1 = fmaf(du1, invR, -f);
      duvA.z = fmaf(-coef1, ctr.y, cL * lp1.x);
      duvA.w = fmaf(coef1, ctr.x, -halfInvR * dk1) + cL * lp1.y;
      dTv.y = -(invR * d1c.z) * ctr.y + cL * lp1.z;
      dqv.y = fmaf(-(invR * d1c.w), ctr.y, cL * lp1.w);
      wsA.z = invR * d1c.y * dpk; wsA.w = d1c.z;
    }
    {
      float4 d1c = d1S[ty + 2][tx * 4 + 4];
      float4 ctr = S4[ty + 4][tx * 4 + 6];
      float coef1 = fmaf(du2, invR, -f);
      duvB.x = fmaf(-coef1, ctr.y, cL * lp2.x);
      duvB.y = fmaf(coef1, ctr.x, -halfInvR * dk2) + cL * lp2.y;
      dTv.z = -(invR * d1c.z) * ctr.y + cL * lp2.z;
      dqv.z = fmaf(-(invR * d1c.w), ctr.y, cL * lp2.w);
      wsB.x = invR * d1c.y * dpk; wsB.y = d1c.z;
    }
    {
      float4 d1c = d1S[ty + 2][tx * 4 + 5];
      float4 ctr = S4[ty + 4][tx * 4 + 7];
      float coef1 = fmaf(du3, invR, -f);
      duvB.z = fmaf(-coef1, ctr.y, cL * lp3.x);
      duvB.w = fmaf(coef1, ctr.x, -halfInvR * dk3) + cL * lp3.y;
      dTv.w = -(invR * d1c.z) * ctr.y + cL * lp3.z;
      dqv.w = fmaf(-(invR * d1c.w), ctr.y, cL * lp3.w);
      wsB.z = invR * d1c.y * dpk; wsB.w = d1c.z;
    }
    const int gidx = (k * Hh + h) * Ww + wbase;
    float4* o4 = (float4*)out;
    o4[gidx >> 1] = duvA;
    o4[(gidx >> 1) + 1] = duvB;
    *(float4*)&out[OFF_DT + gidx] = dTv;
    *(float4*)&out[OFF_DQ + gidx] = dqv;
    float4* w4 = (float4*)ws;
    w4[gidx >> 1] = wsA;
    w4[(gidx >> 1) + 1] = wsB;
  }
}

// ---------------------------------------------------------------- pass 2 ----
__global__ __launch_bounds__(256) void pe_pass2(
    const float* __restrict__ Tg,
    const float* __restrict__ p_levels,
    const float2* __restrict__ ws,
    float* __restrict__ out)
{
  int i4 = blockIdx.x * 256 + threadIdx.x;   // quad index (4 points/thread)
  if (i4 >= HW / 4) return;
  const float invR = (float)(1.0 / 6371000.0);
  const float RCP = (float)(287.0 / 1004.0);

  float pl[Kz];
  #pragma unroll
  for (int k = 0; k < Kz; ++k) pl[k] = p_levels[k];

  const float4* T4 = (const float4*)Tg;
  const float4* ws4 = (const float4*)ws;
  float4* o4 = (float4*)out;
  float4* dT4 = (float4*)(out + OFF_DT);

  float4 cum = {0,0,0,0}, sumT = {0,0,0,0};
  float4 Tm = {0,0,0,0}, Tc = T4[i4];

  #pragma unroll
  for (int k = 0; k < Kz; ++k) {
    float4 Tp = (k < Kz - 1) ? T4[(k + 1) * (HW / 4) + i4] : make_float4(0,0,0,0);
    float4 wa = ws4[k * (HW / 2) + 2 * i4];
    float4 wb = ws4[k * (HW / 2) + 2 * i4 + 1];
    float om0 = fmaf(0.5f, wa.x, cum.x); cum.x += wa.x;
    float om1 = fmaf(0.5f, wa.z, cum.y); cum.y += wa.z;
    float om2 = fmaf(0.5f, wb.x, cum.z); cum.z += wb.x;
    float om3 = fmaf(0.5f, wb.z, cum.w); cum.w += wb.z;

    float4 dTdp;
    if (k == 0) {
      float idp = 1.f / (pl[1] - pl[0]);
      dTdp.x = (Tp.x - Tc.x) * idp; dTdp.y = (Tp.y - Tc.y) * idp;
      dTdp.z = (Tp.z - Tc.z) * idp; dTdp.w = (Tp.w - Tc.w) * idp;
    } else if (k == Kz - 1) {
      float idp = 1.f / (pl[Kz - 1] - pl[Kz - 2]);
      dTdp.x = (Tc.x - Tm.x) * idp; dTdp.y = (Tc.y - Tm.y) * idp;
      dTdp.z = (Tc.z - Tm.z) * idp; dTdp.w = (Tc.w - Tm.w) * idp;
    } else {
      float idp = 1.f / (pl[k + 1] - pl[k - 1]);
      dTdp.x = (Tp.x - Tm.x) * idp; dTdp.y = (Tp.y - Tm.y) * idp;
      dTdp.z = (Tp.z - Tm.z) * idp; dTdp.w = (Tp.w - Tm.w) * idp;
    }
    float iplk = RCP / pl[k];
    float4 dt = dT4[k * (HW / 4) + i4];
    dt.x += om0 * fmaf(iplk, Tc.x, -dTdp.x);
    dt.y += om1 * fmaf(iplk, Tc.y, -dTdp.y);
    dt.z += om2 * fmaf(iplk, Tc.z, -dTdp.z);
    dt.w += om3 * fmaf(iplk, Tc.w, -dTdp.w);
    dT4[k * (HW / 4) + i4] = dt;

    float4 oa = o4[k * (HW / 2) + 2 * i4];
    float4 ob = o4[k * (HW / 2) + 2 * i4 + 1];
    oa.y += sumT.x; oa.w += sumT.y;
    ob.y += sumT.z; ob.w += sumT.w;
    o4[k * (HW / 2) + 2 * i4] = oa;
    o4[k * (HW / 2) + 2 * i4 + 1] = ob;

    if (k < Kz - 1) {
      float c = -287.0f * logf(pl[k] / pl[k + 1]) * invR;
      sumT.x = fmaf(c, wa.y, sumT.x);
      sumT.y = fmaf(c, wa.w, sumT.y);
      sumT.z = fmaf(c, wb.y, sumT.z);
      sumT.w = fmaf(c, wb.w, sumT.w);
    }
    Tm = Tc; Tc = Tp;
  }
}

// ------------------------------------------------- fallback fused kernel ----
constexpr int FTH = 16, FTW = 16;
constexpr int FSH = FTH + 8, FSW = FTW + 8;
constexpr int FEH = FTH + 4, FEW = FTW + 4;
constexpr int FSWp = FSW + 1, FEWp = FEW + 1;

__global__ __launch_bounds__(256) void pe_step(
    const float2* __restrict__ uv,
    const float*  __restrict__ Tg,
    const float*  __restrict__ qg,
    const float*  __restrict__ psi,
    const float*  __restrict__ quad,
    const float*  __restrict__ f_cor,
    const float*  __restrict__ p_levels,
    const float*  __restrict__ delta_p,
    float* __restrict__ out)
{
  __shared__ float uS[FSH][FSWp], vS[FSH][FSWp], TS[FSH][FSWp], qS[FSH][FSWp];
  __shared__ float keS[FEH][FEWp];
  __shared__ float d1uS[FEH][FEWp], d1vS[FEH][FEWp], d1TS[FEH][FEWp], d1qS[FEH][FEWp];
  __shared__ float P1L[FEH][25];
  __shared__ float P0L[FTH][25];
  __shared__ float quadA[FSH];
  __shared__ float pl[8], dps[8];

  const int tid = threadIdx.x;
  const int tx = tid & (FTW - 1);
  const int ty = tid >> 4;
  const int w0 = blockIdx.x * FTW;
  const int h0 = blockIdx.y * FTH;

  if (tid < FSH) quadA[tid] = quad[clipH(h0 + tid - 4)];
  if (tid < 8) { pl[tid] = p_levels[tid]; dps[tid] = delta_p[tid]; }
  for (int idx = tid; idx < FEH * 25; idx += 256) {
    int ee = idx / 25, t = idx - ee * 25;
    int p = clipH(h0 + ee - 2);
    float s = 0.f;
    #pragma unroll
    for (int kk = 0; kk < 5; ++kk)
      s += psi[kk * (2 * Hh * 25) + Hh * 25 + p * 25 + t];
    P1L[ee][t] = s;
  }
  for (int idx = tid; idx < FTH * 25; idx += 256) {
    int r = idx / 25, t = idx - r * 25;
    int p = clipH(h0 + r);
    float s = 0.f;
    #pragma unroll
    for (int kk = 0; kk < 5; ++kk)
      s += psi[kk * (2 * Hh * 25) + p * 25 + t];
    P0L[r][t] = s;
  }
  __syncthreads();

  const int h = h0 + ty;
  const bool act = h < Hh;
  const int hc = act ? h : (Hh - 1);
  const int w = w0 + tx;
  const float f = f_cor[hc];
  const float invR = (float)(1.0 / 6371000.0);
  const float cL = 200000.0f * invR * invR;
  const float RCP = (float)(287.0 / 1004.0);

  float cum = 0.f;
  float sumT = 0.f;

  #pragma unroll 1
  for (int k = 0; k < Kz; ++k) {
    __syncthreads();
    for (int idx = tid; idx < FSH * FSW; idx += 256) {
      int rr = idx / FSW, cc = idx - rr * FSW;
      int pr = clipH(h0 + rr - 4);
      int pc = w0 + cc - 4;
      pc = pc < 0 ? pc + Ww : (pc >= Ww ? pc - Ww : pc);
      int g = (k * Hh + pr) * Ww + pc;
      float2 uvv = uv[g];
      uS[rr][cc] = uvv.x; vS[rr][cc] = uvv.y;
      TS[rr][cc] = Tg[g]; qS[rr][cc] = qg[g];
    }
    __syncthreads();
    for (int idx = tid; idx < FEH * FEW; idx += 256) {
      int ee = idx / FEW, ec = idx - ee * FEW;
      float su = uS[ee + 2][ec + 2], sv = vS[ee + 2][ec + 2];
      keS[ee][ec] = 0.5f * (su * su + sv * sv);
    }
    for (int idx = tid; idx < FEH * FEW; idx += 256) {
      int ee = idx / FEW, ec = idx - ee * FEW;
      int p = clipH(h0 + ee - 2);
      float au = 0.f, av = 0.f, aT = 0.f, aq = 0.f;
      #pragma unroll
      for (int dl = 0; dl < 5; ++dl) {
        int sp = clipH(p + dl - 2);
        int rr = sp - h0 + 4;
        float qv = quadA[rr];
        float ru = 0.f, rv = 0.f, rT = 0.f, rq = 0.f;
        #pragma unroll
        for (int dw = 0; dw < 5; ++dw) {
          float wgt = P1L[ee][dl * 5 + dw];
          ru = fmaf(wgt, uS[rr][ec + dw], ru);
          rv = fmaf(wgt, vS[rr][ec + dw], rv);
          rT = fmaf(wgt, TS[rr][ec + dw], rT);
          rq = fmaf(wgt, qS[rr][ec + dw], rq);
        }
        au = fmaf(qv, ru, au); av = fmaf(qv, rv, av);
        aT = fmaf(qv, rT, aT); aq = fmaf(qv, rq, aq);
      }
      d1uS[ee][ec] = au; d1vS[ee][ec] = av;
      d1TS[ee][ec] = aT; d1qS[ee][ec] = aq;
    }
    __syncthreads();

    float d0u = 0.f, d1ke = 0.f;
    #pragma unroll
    for (int dl = 0; dl < 5; ++dl) {
      int sp = clipH(hc + dl - 2);
      int rr = sp - h0 + 4;
      int er = sp - h0 + 2;
      float qv = quadA[rr];
      float r0 = 0.f, rk = 0.f;
      #pragma unroll
      for (int dw = 0; dw < 5; ++dw) {
        r0 = fmaf(P0L[ty][dl * 5 + dw], uS[rr][tx + 2 + dw], r0);
        rk = fmaf(P1L[ty + 2][dl * 5 + dw], keS[er][tx + dw], rk);
      }
      d0u = fmaf(qv, r0, d0u);
      d1ke = fmaf(qv, rk, d1ke);
    }

    float lapu = 0.f, lapv = 0.f, lapT = 0.f, lapq = 0.f;
    #pragma unroll
    for (int dl = 0; dl < 5; ++dl) {
      int sp = clipH(hc + dl - 2);
      int er = sp - h0 + 2;
      float qv = quadA[er + 2];
      float ru = 0.f, rv = 0.f, rT = 0.f, rq = 0.f;
      #pragma unroll
      for (int dw = 0; dw < 5; ++dw) {
        float wgt = P1L[ty + 2][dl * 5 + dw];
        ru = fmaf(wgt, d1uS[er][tx + dw], ru);
        rv = fmaf(wgt, d1vS[er][tx + dw], rv);
        rT = fmaf(wgt, d1TS[er][tx + dw], rT);
        rq = fmaf(wgt, d1qS[er][tx + dw], rq);
      }
      lapu = fmaf(qv, ru, lapu); lapv = fmaf(qv, rv, lapv);
      lapT = fmaf(qv, rT, lapT); lapq = fmaf(qv, rq, lapq);
    }

    float d1T_c = d1TS[ty + 2][tx + 2];
    float d1v_c = d1vS[ty + 2][tx + 2];
    float d1q_c = d1qS[ty + 2][tx + 2];
    float uc = uS[ty + 4][tx + 4], vc = vS[ty + 4][tx + 4];
    float Tc = TS[ty + 4][tx + 4];

    float coef1 = fmaf(d0u, invR, -f);
    float duv0 = fmaf(-coef1, vc, cL * lapu);
    float yv1 = fmaf(-invR, d1ke, sumT);
    float duv1 = fmaf(coef1, uc, yv1) + cL * lapv;

    float div = invR * d1v_c;
    float dpk = dps[k];
    float omega = fmaf(0.5f * div, dpk, cum);
    cum = fmaf(div, dpk, cum);

    int gidx = (k * Hh + hc) * Ww + w;
    float dTdp;
    if (k == 0) {
      float Tp = Tg[gidx + HW];
      dTdp = (Tp - Tc) / (pl[1] - pl[0]);
    } else if (k == Kz - 1) {
      float Tm = Tg[gidx - HW];
      dTdp = (Tc - Tm) / (pl[Kz - 1] - pl[Kz - 2]);
    } else {
      float Tp = Tg[gidx + HW];
      float Tm = Tg[gidx - HW];
      dTdp = (Tp - Tm) / (pl[k + 1] - pl[k - 1]);
    }
    float adv = -(invR * d1T_c) * vc;
    float dT = adv + omega * ((RCP * Tc) / pl[k] - dTdp) + cL * lapT;
    float dq = fmaf(-(invR * d1q_c), vc, cL * lapq);

    if (act) {
      ((float2*)out)[(k * Hh + h) * Ww + w] = make_float2(duv0, duv1);
      out[OFF_DT + gidx] = dT;
      out[OFF_DQ + gidx] = dq;
    }

    if (k < Kz - 1) {
      float lpr = logf(pl[k] / pl[k + 1]);
      float wTk = (float)(-287.0 * (double)lpr / 6371000.0);
      sumT = fmaf(wTk, d1T_c, sumT);
    }
  }
}

extern "C" void kernel_launch(void* const* d_in, const int* in_sizes, int n_in,
                              void* d_out, int out_size, void* d_ws, size_t ws_size,
                              hipStream_t stream) {
  (void)in_sizes; (void)n_in; (void)out_size;
  const float2* uv   = (const float2*)d_in[0];
  const float*  T    = (const float*) d_in[1];
  const float*  q    = (const float*) d_in[2];
  const float*  psi  = (const float*) d_in[3];
  const float*  quad = (const float*) d_in[4];
  const float*  fc   = (const float*) d_in[5];
  const float*  pl   = (const float*) d_in[6];
  const float*  dp   = (const float*) d_in[7];

  const size_t ws_div_floats = (size_t)2 * Kz * HW;        // K*HW float2
  const size_t pq_floats = (size_t)Hh * PQROW;             // 14440
  const size_t ws_need = (ws_div_floats + 2 * pq_floats) * sizeof(float);
  if (ws_size >= ws_need) {
    float* wsF = (float*)d_ws;
    float* P0g = wsF + ws_div_floats;
    float* P1g = P0g + pq_floats;

    dim3 gt1((Hh * PQROW + 255) / 256);                    // 57 blocks
    hipLaunchKernelGGL(pe_tab_pq, gt1, dim3(256), 0, stream, psi, quad, P0g, P1g);

    dim3 g1(GX, GY, Kz);                                   // 23 x 12 x 8
    hipLaunchKernelGGL(pe_pass1, g1, dim3(NTHR), 0, stream,
                       uv, T, q, P0g, P1g, fc, dp, (float*)d_out, (float2*)d_ws);

    dim3 g2((HW / 4 + 255) / 256);
    hipLaunchKernelGGL(pe_pass2, g2, dim3(256), 0, stream,
                       T, pl, (const float2*)d_ws, (float*)d_out);
  } else {
    dim3 grid(Ww / FTW, (Hh + FTH - 1) / FTH);
    hipLaunchKernelGGL(pe_step, grid, dim3(256), 0, stream,
                       uv, T, q, psi, quad, fc, pl, dp, (float*)d_out);
  }
}

// Round 17
// 67.700 us; speedup vs baseline: 1.4257x; 1.0028x over previous
//
#include <hip/hip_runtime.h>

// Primitive-equations block stepper, gfx950 — R17.
// = R16 (32x32 tile two-stage, best config) with ONE change: S4 row stride
// 41 -> 43. Bank math: 4*41 ≡ 4 (mod 32) made stencil2's S4 re-read 4-way
// bank-conflicted (even-tx lanes share a 4-bank group per row pair);
// 4*43 ≡ 12 (mod 32) has period 8 over consecutive rows -> conflict-free.
// (d1S stride 37, 4*37 ≡ 20, was already conflict-free — matches R15's
// diagnostic where removing only the S4 re-read zeroed the counter.)

constexpr int Kz = 8, Hh = 361, Ww = 720;
constexpr int HW = Hh * Ww;              // 259920
constexpr int OFF_DT = Kz * HW * 2;      // 4158720
constexpr int OFF_DQ = OFF_DT + Kz * HW; // 6238080

// ---- pass-1 geometry ----
constexpr int TH = 32, TW = 32;          // outputs per block
constexpr int NTHR = 256;                // 8 thread-cols x 32 rows, 4 waves
constexpr int NCOL = 8;                  // thread columns (4 outputs each)
constexpr int SH = TH + 8, SW4 = TW + 8; // staged region 40 x 40 points
constexpr int EH = TH + 4, EW4 = TW + 4; // ext D1 region 36 x 36
constexpr int SW4P = 43;                 // S4 row stride: 4*43 mod 32 = 12
constexpr int EW4P = 37;                 // d1S row stride: 4*37 mod 32 = 20
constexpr int PQROW = 40;                // P-table row stride: 5 a-groups x 8
constexpr int GX = (Ww + TW - 1) / TW;   // 23 (last tile partial, guarded)
constexpr int GY = (Hh + TH - 1) / TH;   // 12

__device__ __forceinline__ int clipH(int x) {
  return x < 0 ? 0 : (x > Hh - 1 ? Hh - 1 : x);
}

#define FMA4(acc, s, v)                                                        \
  do {                                                                         \
    acc.x = fmaf((s), (v).x, acc.x);                                           \
    acc.y = fmaf((s), (v).y, acc.y);                                           \
    acc.z = fmaf((s), (v).z, acc.z);                                           \
    acc.w = fmaf((s), (v).w, acc.w);                                           \
  } while (0)

#define ROWV(acc, a, b, c, d, e)                                               \
  do {                                                                         \
    FMA4(acc, wq0, a); FMA4(acc, wq1, b); FMA4(acc, wq2, c);                   \
    FMA4(acc, wq3, d); FMA4(acc, wq4, e);                                      \
  } while (0)

#define ROW5S(acc, q0, q1, q2, q3, q4, a, b, c, d, e)                          \
  acc = fmaf(q0, a, fmaf(q1, b, fmaf(q2, c, fmaf(q3, d, fmaf(q4, e, acc)))))

// ---------------------------------------------------- P0q/P1q tables --------
__global__ __launch_bounds__(256) void pe_tab_pq(
    const float* __restrict__ psi,
    const float* __restrict__ quad,
    float* __restrict__ P0g,
    float* __restrict__ P1g)
{
  int idx = blockIdx.x * 256 + threadIdx.x;   // h*40 + a*8 + b
  if (idx >= Hh * PQROW) return;
  int h = idx / PQROW, o = idx - h * PQROW;
  int a = o >> 3, b = o & 7;
  float v0 = 0.f, v1 = 0.f;
  if (b < 5) {
    #pragma unroll
    for (int kk = 0; kk < 5; ++kk) {
      v0 += psi[kk * (2 * Hh * 25) + h * 25 + a * 5 + b];
      v1 += psi[kk * (2 * Hh * 25) + Hh * 25 + h * 25 + a * 5 + b];
    }
    float qv = quad[clipH(h + a - 2)];
    v0 *= qv; v1 *= qv;
  }
  P0g[idx] = v0;
  P1g[idx] = v1;
}

// ---------------------------------------------------------------- pass 1 ----
__global__ __launch_bounds__(NTHR) void pe_pass1(
    const float2* __restrict__ uv,
    const float*  __restrict__ Tg,
    const float*  __restrict__ qg,
    const float*  __restrict__ P0g,
    const float*  __restrict__ P1g,
    const float*  __restrict__ f_cor,
    const float*  __restrict__ delta_p,
    float* __restrict__ out,
    float2* __restrict__ ws)
{
  __shared__ float4 S4[SH][SW4P];       // (u,v,T,q), 26.9 KB
  __shared__ float4 d1S[EH][EW4P];      // (d1u,d1v,d1T,d1q), 21.3 KB

  const int tid = threadIdx.x;
  const int tx = tid % NCOL;            // thread col (owns 4 outputs)
  const int ty = tid / NCOL;            // thread row 0..31
  const int w0 = blockIdx.x * TW;
  const int h0 = blockIdx.y * TH;
  const int k  = blockIdx.z;

  // ---- stage (u,v,T,q) as float4 with +-4 halo (clip lat, wrap lon) ----
  for (int idx = tid; idx < SH * SW4; idx += NTHR) {
    int rr = idx / SW4, cc = idx - rr * SW4;
    int pr = clipH(h0 + rr - 4);
    int pc = w0 + cc - 4;
    pc = pc < 0 ? pc + Ww : (pc >= Ww ? pc - Ww : pc);
    int g = (k * Hh + pr) * Ww + pc;
    float2 uvv = uv[g];
    S4[rr][cc] = make_float4(uvv.x, uvv.y, Tg[g], qg[g]);
  }
  __syncthreads();

  // ---- extended D1 of (u,v,T,q): 36 x 9 groups, ee-fastest lane map ----
  for (int idx = tid; idx < EH * (EW4 / 4); idx += NTHR) {
    int ee = idx % EH;                  // row fastest -> wave spans rows
    int gc = idx / EH;                  // 0..8
    int cb = gc * 4;
    int p = clipH(h0 + ee - 2);
    const float* Pr = P1g + p * PQROW;
    float4 a0 = {0,0,0,0}, a1 = {0,0,0,0}, a2 = {0,0,0,0}, a3 = {0,0,0,0};
    #pragma unroll
    for (int dl = 0; dl < 5; ++dl) {
      int sp = clipH(p + dl - 2);
      int rr = sp - h0 + 4;
      const float4* row = &S4[rr][cb];
      float4 g0 = row[0], g1 = row[1], g2 = row[2], g3 = row[3];
      float4 g4 = row[4], g5 = row[5], g6 = row[6], g7 = row[7];
      float4 wA = *(const float4*)(Pr + dl * 8);
      float wq0 = wA.x, wq1 = wA.y, wq2 = wA.z, wq3 = wA.w;
      float wq4 = Pr[dl * 8 + 4];
      ROWV(a0, g0, g1, g2, g3, g4);
      ROWV(a1, g1, g2, g3, g4, g5);
      ROWV(a2, g2, g3, g4, g5, g6);
      ROWV(a3, g3, g4, g5, g6, g7);
    }
    d1S[ee][cb + 0] = a0; d1S[ee][cb + 1] = a1;
    d1S[ee][cb + 2] = a2; d1S[ee][cb + 3] = a3;
  }
  __syncthreads();

  const int h = h0 + ty;
  const int hc = h < Hh ? h : (Hh - 1);
  const int wbase = w0 + tx * 4;
  const float f = f_cor[hc];
  const float invR = (float)(1.0 / 6371000.0);
  const float halfInvR = 0.5f * invR;
  const float cL = 200000.0f * invR * invR;
  const float* Pr1 = P1g + hc * PQROW;
  const float* Pr0 = P0g + hc * PQROW;

  // ---- second stencil: laplacians (d1S), D0(u) & D1(u^2+v^2) (S4) ----
  float4 lp0 = {0,0,0,0}, lp1 = {0,0,0,0}, lp2 = {0,0,0,0}, lp3 = {0,0,0,0};
  float du0 = 0.f, du1 = 0.f, du2 = 0.f, du3 = 0.f;   // D0(u)
  float dk0 = 0.f, dk1 = 0.f, dk2 = 0.f, dk3 = 0.f;   // D1(u^2+v^2)
  #pragma unroll
  for (int dl = 0; dl < 5; ++dl) {
    int sp = clipH(hc + dl - 2);
    int er = sp - h0 + 2;               // d1S row
    int rr = er + 2;                    // S4 row
    float4 wA = *(const float4*)(Pr1 + dl * 8);
    float wq0 = wA.x, wq1 = wA.y, wq2 = wA.z, wq3 = wA.w;
    float wq4 = Pr1[dl * 8 + 4];
    {
      const float4* row = &d1S[er][tx * 4];
      float4 g0 = row[0], g1 = row[1], g2 = row[2], g3 = row[3];
      float4 g4 = row[4], g5 = row[5], g6 = row[6], g7 = row[7];
      ROWV(lp0, g0, g1, g2, g3, g4);
      ROWV(lp1, g1, g2, g3, g4, g5);
      ROWV(lp2, g2, g3, g4, g5, g6);
      ROWV(lp3, g3, g4, g5, g6, g7);
    }
    {
      const float4* srow = &S4[rr][tx * 4 + 2];
      float4 s0 = srow[0], s1 = srow[1], s2 = srow[2], s3 = srow[3];
      float4 s4 = srow[4], s5 = srow[5], s6 = srow[6], s7 = srow[7];
      float k0 = fmaf(s0.y, s0.y, s0.x * s0.x);
      float k1 = fmaf(s1.y, s1.y, s1.x * s1.x);
      float k2 = fmaf(s2.y, s2.y, s2.x * s2.x);
      float k3 = fmaf(s3.y, s3.y, s3.x * s3.x);
      float k4 = fmaf(s4.y, s4.y, s4.x * s4.x);
      float k5 = fmaf(s5.y, s5.y, s5.x * s5.x);
      float k6 = fmaf(s6.y, s6.y, s6.x * s6.x);
      float k7 = fmaf(s7.y, s7.y, s7.x * s7.x);
      ROW5S(dk0, wq0, wq1, wq2, wq3, wq4, k0, k1, k2, k3, k4);
      ROW5S(dk1, wq0, wq1, wq2, wq3, wq4, k1, k2, k3, k4, k5);
      ROW5S(dk2, wq0, wq1, wq2, wq3, wq4, k2, k3, k4, k5, k6);
      ROW5S(dk3, wq0, wq1, wq2, wq3, wq4, k3, k4, k5, k6, k7);
      float4 w0A = *(const float4*)(Pr0 + dl * 8);
      float q0 = w0A.x, q1 = w0A.y, q2 = w0A.z, q3 = w0A.w;
      float q4 = Pr0[dl * 8 + 4];
      ROW5S(du0, q0, q1, q2, q3, q4, s0.x, s1.x, s2.x, s3.x, s4.x);
      ROW5S(du1, q0, q1, q2, q3, q4, s1.x, s2.x, s3.x, s4.x, s5.x);
      ROW5S(du2, q0, q1, q2, q3, q4, s2.x, s3.x, s4.x, s5.x, s6.x);
      ROW5S(du3, q0, q1, q2, q3, q4, s3.x, s4.x, s5.x, s6.x, s7.x);
    }
  }

  if (h < Hh && wbase < Ww) {
    const float dpk = delta_p[k];
    float4 duvA, duvB, dTv, dqv, wsA, wsB;
    {
      float4 d1c = d1S[ty + 2][tx * 4 + 2];
      float4 ctr = S4[ty + 4][tx * 4 + 4];
      float coef1 = fmaf(du0, invR, -f);
      duvA.x = fmaf(-coef1, ctr.y, cL * lp0.x);
      duvA.y = fmaf(coef1, ctr.x, -halfInvR * dk0) + cL * lp0.y;
      dTv.x = -(invR * d1c.z) * ctr.y + cL * lp0.z;
      dqv.x = fmaf(-(invR * d1c.w), ctr.y, cL * lp0.w);
      wsA.x = invR * d1c.y * dpk; wsA.y = d1c.z;
    }
    {
      float4 d1c = d1S[ty + 2][tx * 4 + 3];
      float4 ctr = S4[ty + 4][tx * 4 + 5];
      float coef1 = fmaf(du1, invR, -f);
      duvA.z = fmaf(-coef1, ctr.y, cL * lp1.x);
      duvA.w = fmaf(coef1, ctr.x, -halfInvR * dk1) + cL * lp1.y;
      dTv.y = -(invR * d1c.z) * ctr.y + cL * lp1.z;
      dqv.y = fmaf(-(invR * d1c.w), ctr.y, cL * lp1.w);
      wsA.z = invR * d1c.y * dpk; wsA.w = d1c.z;
    }
    {
      float4 d1c = d1S[ty + 2][tx * 4 + 4];
      float4 ctr = S4[ty + 4][tx * 4 + 6];
      float coef1 = fmaf(du2, invR, -f);
      duvB.x = fmaf(-coef1, ctr.y, cL * lp2.x);
      duvB.y = fmaf(coef1, ctr.x, -halfInvR * dk2) + cL * lp2.y;
      dTv.z = -(invR * d1c.z) * ctr.y + cL * lp2.z;
      dqv.z = fmaf(-(invR * d1c.w), ctr.y, cL * lp2.w);
      wsB.x = invR * d1c.y * dpk; wsB.y = d1c.z;
    }
    {
      float4 d1c = d1S[ty + 2][tx * 4 + 5];
      float4 ctr = S4[ty + 4][tx * 4 + 7];
      float coef1 = fmaf(du3, invR, -f);
      duvB.z = fmaf(-coef1, ctr.y, cL * lp3.x);
      duvB.w = fmaf(coef1, ctr.x, -halfInvR * dk3) + cL * lp3.y;
      dTv.w = -(invR * d1c.z) * ctr.y + cL * lp3.z;
      dqv.w = fmaf(-(invR * d1c.w), ctr.y, cL * lp3.w);
      wsB.z = invR * d1c.y * dpk; wsB.w = d1c.z;
    }
    const int gidx = (k * Hh + h) * Ww + wbase;
    float4* o4 = (float4*)out;
    o4[gidx >> 1] = duvA;
    o4[(gidx >> 1) + 1] = duvB;
    *(float4*)&out[OFF_DT + gidx] = dTv;
    *(float4*)&out[OFF_DQ + gidx] = dqv;
    float4* w4 = (float4*)ws;
    w4[gidx >> 1] = wsA;
    w4[(gidx >> 1) + 1] = wsB;
  }
}

// ---------------------------------------------------------------- pass 2 ----
__global__ __launch_bounds__(256) void pe_pass2(
    const float* __restrict__ Tg,
    const float* __restrict__ p_levels,
    const float2* __restrict__ ws,
    float* __restrict__ out)
{
  int i4 = blockIdx.x * 256 + threadIdx.x;   // quad index (4 points/thread)
  if (i4 >= HW / 4) return;
  const float invR = (float)(1.0 / 6371000.0);
  const float RCP = (float)(287.0 / 1004.0);

  float pl[Kz];
  #pragma unroll
  for (int k = 0; k < Kz; ++k) pl[k] = p_levels[k];

  const float4* T4 = (const float4*)Tg;
  const float4* ws4 = (const float4*)ws;
  float4* o4 = (float4*)out;
  float4* dT4 = (float4*)(out + OFF_DT);

  float4 cum = {0,0,0,0}, sumT = {0,0,0,0};
  float4 Tm = {0,0,0,0}, Tc = T4[i4];

  #pragma unroll
  for (int k = 0; k < Kz; ++k) {
    float4 Tp = (k < Kz - 1) ? T4[(k + 1) * (HW / 4) + i4] : make_float4(0,0,0,0);
    float4 wa = ws4[k * (HW / 2) + 2 * i4];
    float4 wb = ws4[k * (HW / 2) + 2 * i4 + 1];
    float om0 = fmaf(0.5f, wa.x, cum.x); cum.x += wa.x;
    float om1 = fmaf(0.5f, wa.z, cum.y); cum.y += wa.z;
    float om2 = fmaf(0.5f, wb.x, cum.z); cum.z += wb.x;
    float om3 = fmaf(0.5f, wb.z, cum.w); cum.w += wb.z;

    float4 dTdp;
    if (k == 0) {
      float idp = 1.f / (pl[1] - pl[0]);
      dTdp.x = (Tp.x - Tc.x) * idp; dTdp.y = (Tp.y - Tc.y) * idp;
      dTdp.z = (Tp.z - Tc.z) * idp; dTdp.w = (Tp.w - Tc.w) * idp;
    } else if (k == Kz - 1) {
      float idp = 1.f / (pl[Kz - 1] - pl[Kz - 2]);
      dTdp.x = (Tc.x - Tm.x) * idp; dTdp.y = (Tc.y - Tm.y) * idp;
      dTdp.z = (Tc.z - Tm.z) * idp; dTdp.w = (Tc.w - Tm.w) * idp;
    } else {
      float idp = 1.f / (pl[k + 1] - pl[k - 1]);
      dTdp.x = (Tp.x - Tm.x) * idp; dTdp.y = (Tp.y - Tm.y) * idp;
      dTdp.z = (Tp.z - Tm.z) * idp; dTdp.w = (Tp.w - Tm.w) * idp;
    }
    float iplk = RCP / pl[k];
    float4 dt = dT4[k * (HW / 4) + i4];
    dt.x += om0 * fmaf(iplk, Tc.x, -dTdp.x);
    dt.y += om1 * fmaf(iplk, Tc.y, -dTdp.y);
    dt.z += om2 * fmaf(iplk, Tc.z, -dTdp.z);
    dt.w += om3 * fmaf(iplk, Tc.w, -dTdp.w);
    dT4[k * (HW / 4) + i4] = dt;

    float4 oa = o4[k * (HW / 2) + 2 * i4];
    float4 ob = o4[k * (HW / 2) + 2 * i4 + 1];
    oa.y += sumT.x; oa.w += sumT.y;
    ob.y += sumT.z; ob.w += sumT.w;
    o4[k * (HW / 2) + 2 * i4] = oa;
    o4[k * (HW / 2) + 2 * i4 + 1] = ob;

    if (k < Kz - 1) {
      float c = -287.0f * logf(pl[k] / pl[k + 1]) * invR;
      sumT.x = fmaf(c, wa.y, sumT.x);
      sumT.y = fmaf(c, wa.w, sumT.y);
      sumT.z = fmaf(c, wb.y, sumT.z);
      sumT.w = fmaf(c, wb.w, sumT.w);
    }
    Tm = Tc; Tc = Tp;
  }
}

// ------------------------------------------------- fallback fused kernel ----
constexpr int FTH = 16, FTW = 16;
constexpr int FSH = FTH + 8, FSW = FTW + 8;
constexpr int FEH = FTH + 4, FEW = FTW + 4;
constexpr int FSWp = FSW + 1, FEWp = FEW + 1;

__global__ __launch_bounds__(256) void pe_step(
    const float2* __restrict__ uv,
    const float*  __restrict__ Tg,
    const float*  __restrict__ qg,
    const float*  __restrict__ psi,
    const float*  __restrict__ quad,
    const float*  __restrict__ f_cor,
    const float*  __restrict__ p_levels,
    const float*  __restrict__ delta_p,
    float* __restrict__ out)
{
  __shared__ float uS[FSH][FSWp], vS[FSH][FSWp], TS[FSH][FSWp], qS[FSH][FSWp];
  __shared__ float keS[FEH][FEWp];
  __shared__ float d1uS[FEH][FEWp], d1vS[FEH][FEWp], d1TS[FEH][FEWp], d1qS[FEH][FEWp];
  __shared__ float P1L[FEH][25];
  __shared__ float P0L[FTH][25];
  __shared__ float quadA[FSH];
  __shared__ float pl[8], dps[8];

  const int tid = threadIdx.x;
  const int tx = tid & (FTW - 1);
  const int ty = tid >> 4;
  const int w0 = blockIdx.x * FTW;
  const int h0 = blockIdx.y * FTH;

  if (tid < FSH) quadA[tid] = quad[clipH(h0 + tid - 4)];
  if (tid < 8) { pl[tid] = p_levels[tid]; dps[tid] = delta_p[tid]; }
  for (int idx = tid; idx < FEH * 25; idx += 256) {
    int ee = idx / 25, t = idx - ee * 25;
    int p = clipH(h0 + ee - 2);
    float s = 0.f;
    #pragma unroll
    for (int kk = 0; kk < 5; ++kk)
      s += psi[kk * (2 * Hh * 25) + Hh * 25 + p * 25 + t];
    P1L[ee][t] = s;
  }
  for (int idx = tid; idx < FTH * 25; idx += 256) {
    int r = idx / 25, t = idx - r * 25;
    int p = clipH(h0 + r);
    float s = 0.f;
    #pragma unroll
    for (int kk = 0; kk < 5; ++kk)
      s += psi[kk * (2 * Hh * 25) + p * 25 + t];
    P0L[r][t] = s;
  }
  __syncthreads();

  const int h = h0 + ty;
  const bool act = h < Hh;
  const int hc = act ? h : (Hh - 1);
  const int w = w0 + tx;
  const float f = f_cor[hc];
  const float invR = (float)(1.0 / 6371000.0);
  const float cL = 200000.0f * invR * invR;
  const float RCP = (float)(287.0 / 1004.0);

  float cum = 0.f;
  float sumT = 0.f;

  #pragma unroll 1
  for (int k = 0; k < Kz; ++k) {
    __syncthreads();
    for (int idx = tid; idx < FSH * FSW; idx += 256) {
      int rr = idx / FSW, cc = idx - rr * FSW;
      int pr = clipH(h0 + rr - 4);
      int pc = w0 + cc - 4;
      pc = pc < 0 ? pc + Ww : (pc >= Ww ? pc - Ww : pc);
      int g = (k * Hh + pr) * Ww + pc;
      float2 uvv = uv[g];
      uS[rr][cc] = uvv.x; vS[rr][cc] = uvv.y;
      TS[rr][cc] = Tg[g]; qS[rr][cc] = qg[g];
    }
    __syncthreads();
    for (int idx = tid; idx < FEH * FEW; idx += 256) {
      int ee = idx / FEW, ec = idx - ee * FEW;
      float su = uS[ee + 2][ec + 2], sv = vS[ee + 2][ec + 2];
      keS[ee][ec] = 0.5f * (su * su + sv * sv);
    }
    for (int idx = tid; idx < FEH * FEW; idx += 256) {
      int ee = idx / FEW, ec = idx - ee * FEW;
      int p = clipH(h0 + ee - 2);
      float au = 0.f, av = 0.f, aT = 0.f, aq = 0.f;
      #pragma unroll
      for (int dl = 0; dl < 5; ++dl) {
        int sp = clipH(p + dl - 2);
        int rr = sp - h0 + 4;
        float qv = quadA[rr];
        float ru = 0.f, rv = 0.f, rT = 0.f, rq = 0.f;
        #pragma unroll
        for (int dw = 0; dw < 5; ++dw) {
          float wgt = P1L[ee][dl * 5 + dw];
          ru = fmaf(wgt, uS[rr][ec + dw], ru);
          rv = fmaf(wgt, vS[rr][ec + dw], rv);
          rT = fmaf(wgt, TS[rr][ec + dw], rT);
          rq = fmaf(wgt, qS[rr][ec + dw], rq);
        }
        au = fmaf(qv, ru, au); av = fmaf(qv, rv, av);
        aT = fmaf(qv, rT, aT); aq = fmaf(qv, rq, aq);
      }
      d1uS[ee][ec] = au; d1vS[ee][ec] = av;
      d1TS[ee][ec] = aT; d1qS[ee][ec] = aq;
    }
    __syncthreads();

    float d0u = 0.f, d1ke = 0.f;
    #pragma unroll
    for (int dl = 0; dl < 5; ++dl) {
      int sp = clipH(hc + dl - 2);
      int rr = sp - h0 + 4;
      int er = sp - h0 + 2;
      float qv = quadA[rr];
      float r0 = 0.f, rk = 0.f;
      #pragma unroll
      for (int dw = 0; dw < 5; ++dw) {
        r0 = fmaf(P0L[ty][dl * 5 + dw], uS[rr][tx + 2 + dw], r0);
        rk = fmaf(P1L[ty + 2][dl * 5 + dw], keS[er][tx + dw], rk);
      }
      d0u = fmaf(qv, r0, d0u);
      d1ke = fmaf(qv, rk, d1ke);
    }

    float lapu = 0.f, lapv = 0.f, lapT = 0.f, lapq = 0.f;
    #pragma unroll
    for (int dl = 0; dl < 5; ++dl) {
      int sp = clipH(hc + dl - 2);
      int er = sp - h0 + 2;
      float qv = quadA[er + 2];
      float ru = 0.f, rv = 0.f, rT = 0.f, rq = 0.f;
      #pragma unroll
      for (int dw = 0; dw < 5; ++dw) {
        float wgt = P1L[ty + 2][dl * 5 + dw];
        ru = fmaf(wgt, d1uS[er][tx + dw], ru);
        rv = fmaf(wgt, d1vS[er][tx + dw], rv);
        rT = fmaf(wgt, d1TS[er][tx + dw], rT);
        rq = fmaf(wgt, d1qS[er][tx + dw], rq);
      }
      lapu = fmaf(qv, ru, lapu); lapv = fmaf(qv, rv, lapv);
      lapT = fmaf(qv, rT, lapT); lapq = fmaf(qv, rq, lapq);
    }

    float d1T_c = d1TS[ty + 2][tx + 2];
    float d1v_c = d1vS[ty + 2][tx + 2];
    float d1q_c = d1qS[ty + 2][tx + 2];
    float uc = uS[ty + 4][tx + 4], vc = vS[ty + 4][tx + 4];
    float Tc = TS[ty + 4][tx + 4];

    float coef1 = fmaf(d0u, invR, -f);
    float duv0 = fmaf(-coef1, vc, cL * lapu);
    float yv1 = fmaf(-invR, d1ke, sumT);
    float duv1 = fmaf(coef1, uc, yv1) + cL * lapv;

    float div = invR * d1v_c;
    float dpk = dps[k];
    float omega = fmaf(0.5f * div, dpk, cum);
    cum = fmaf(div, dpk, cum);

    int gidx = (k * Hh + hc) * Ww + w;
    float dTdp;
    if (k == 0) {
      float Tp = Tg[gidx + HW];
      dTdp = (Tp - Tc) / (pl[1] - pl[0]);
    } else if (k == Kz - 1) {
      float Tm = Tg[gidx - HW];
      dTdp = (Tc - Tm) / (pl[Kz - 1] - pl[Kz - 2]);
    } else {
      float Tp = Tg[gidx + HW];
      float Tm = Tg[gidx - HW];
      dTdp = (Tp - Tm) / (pl[k + 1] - pl[k - 1]);
    }
    float adv = -(invR * d1T_c) * vc;
    float dT = adv + omega * ((RCP * Tc) / pl[k] - dTdp) + cL * lapT;
    float dq = fmaf(-(invR * d1q_c), vc, cL * lapq);

    if (act) {
      ((float2*)out)[(k * Hh + h) * Ww + w] = make_float2(duv0, duv1);
      out[OFF_DT + gidx] = dT;
      out[OFF_DQ + gidx] = dq;
    }

    if (k < Kz - 1) {
      float lpr = logf(pl[k] / pl[k + 1]);
      float wTk = (float)(-287.0 * (double)lpr / 6371000.0);
      sumT = fmaf(wTk, d1T_c, sumT);
    }
  }
}

extern "C" void kernel_launch(void* const* d_in, const int* in_sizes, int n_in,
                              void* d_out, int out_size, void* d_ws, size_t ws_size,
                              hipStream_t stream) {
  (void)in_sizes; (void)n_in; (void)out_size;
  const float2* uv   = (const float2*)d_in[0];
  const float*  T    = (const float*) d_in[1];
  const float*  q    = (const float*) d_in[2];
  const float*  psi  = (const float*) d_in[3];
  const float*  quad = (const float*) d_in[4];
  const float*  fc   = (const float*) d_in[5];
  const float*  pl   = (const float*) d_in[6];
  const float*  dp   = (const float*) d_in[7];

  const size_t ws_div_floats = (size_t)2 * Kz * HW;        // K*HW float2
  const size_t pq_floats = (size_t)Hh * PQROW;             // 14440
  const size_t ws_need = (ws_div_floats + 2 * pq_floats) * sizeof(float);
  if (ws_size >= ws_need) {
    float* wsF = (float*)d_ws;
    float* P0g = wsF + ws_div_floats;
    float* P1g = P0g + pq_floats;

    dim3 gt1((Hh * PQROW + 255) / 256);                    // 57 blocks
    hipLaunchKernelGGL(pe_tab_pq, gt1, dim3(256), 0, stream, psi, quad, P0g, P1g);

    dim3 g1(GX, GY, Kz);                                   // 23 x 12 x 8
    hipLaunchKernelGGL(pe_pass1, g1, dim3(NTHR), 0, stream,
                       uv, T, q, P0g, P1g, fc, dp, (float*)d_out, (float2*)d_ws);

    dim3 g2((HW / 4 + 255) / 256);
    hipLaunchKernelGGL(pe_pass2, g2, dim3(256), 0, stream,
                       T, pl, (const float2*)d_ws, (float*)d_out);
  } else {
    dim3 grid(Ww / FTW, (Hh + FTH - 1) / FTH);
    hipLaunchKernelGGL(pe_step, grid, dim3(256), 0, stream,
                       uv, T, q, psi, quad, fc, pl, dp, (float*)d_out);
  }
}

// Round 18
// 67.429 us; speedup vs baseline: 1.4314x; 1.0040x over previous
//
#include <hip/hip_runtime.h>

// Primitive-equations block stepper, gfx950 — R18.
// = R17 with __launch_bounds__(256, 3) on pe_pass1: VGPR budget (84 <= cap
// 256/3≈85) and LDS (3x49KB=147 <= 160) both allow 3 blocks/CU, but measured
// occupancy was 2 blocks/CU. Force the third resident block. No spill risk:
// cap >= current allocation (unlike R7-R9 where cap 64/128 << ~160 live regs).

constexpr int Kz = 8, Hh = 361, Ww = 720;
constexpr int HW = Hh * Ww;              // 259920
constexpr int OFF_DT = Kz * HW * 2;      // 4158720
constexpr int OFF_DQ = OFF_DT + Kz * HW; // 6238080

// ---- pass-1 geometry ----
constexpr int TH = 32, TW = 32;          // outputs per block
constexpr int NTHR = 256;                // 8 thread-cols x 32 rows, 4 waves
constexpr int NCOL = 8;                  // thread columns (4 outputs each)
constexpr int SH = TH + 8, SW4 = TW + 8; // staged region 40 x 40 points
constexpr int EH = TH + 4, EW4 = TW + 4; // ext D1 region 36 x 36
constexpr int SW4P = 43;                 // S4 row stride
constexpr int EW4P = 37;                 // d1S row stride
constexpr int PQROW = 40;                // P-table row stride: 5 a-groups x 8
constexpr int GX = (Ww + TW - 1) / TW;   // 23 (last tile partial, guarded)
constexpr int GY = (Hh + TH - 1) / TH;   // 12

__device__ __forceinline__ int clipH(int x) {
  return x < 0 ? 0 : (x > Hh - 1 ? Hh - 1 : x);
}

#define FMA4(acc, s, v)                                                        \
  do {                                                                         \
    acc.x = fmaf((s), (v).x, acc.x);                                           \
    acc.y = fmaf((s), (v).y, acc.y);                                           \
    acc.z = fmaf((s), (v).z, acc.z);                                           \
    acc.w = fmaf((s), (v).w, acc.w);                                           \
  } while (0)

#define ROWV(acc, a, b, c, d, e)                                               \
  do {                                                                         \
    FMA4(acc, wq0, a); FMA4(acc, wq1, b); FMA4(acc, wq2, c);                   \
    FMA4(acc, wq3, d); FMA4(acc, wq4, e);                                      \
  } while (0)

#define ROW5S(acc, q0, q1, q2, q3, q4, a, b, c, d, e)                          \
  acc = fmaf(q0, a, fmaf(q1, b, fmaf(q2, c, fmaf(q3, d, fmaf(q4, e, acc)))))

// ---------------------------------------------------- P0q/P1q tables --------
__global__ __launch_bounds__(256) void pe_tab_pq(
    const float* __restrict__ psi,
    const float* __restrict__ quad,
    float* __restrict__ P0g,
    float* __restrict__ P1g)
{
  int idx = blockIdx.x * 256 + threadIdx.x;   // h*40 + a*8 + b
  if (idx >= Hh * PQROW) return;
  int h = idx / PQROW, o = idx - h * PQROW;
  int a = o >> 3, b = o & 7;
  float v0 = 0.f, v1 = 0.f;
  if (b < 5) {
    #pragma unroll
    for (int kk = 0; kk < 5; ++kk) {
      v0 += psi[kk * (2 * Hh * 25) + h * 25 + a * 5 + b];
      v1 += psi[kk * (2 * Hh * 25) + Hh * 25 + h * 25 + a * 5 + b];
    }
    float qv = quad[clipH(h + a - 2)];
    v0 *= qv; v1 *= qv;
  }
  P0g[idx] = v0;
  P1g[idx] = v1;
}

// ---------------------------------------------------------------- pass 1 ----
__global__ __launch_bounds__(NTHR, 3) void pe_pass1(
    const float2* __restrict__ uv,
    const float*  __restrict__ Tg,
    const float*  __restrict__ qg,
    const float*  __restrict__ P0g,
    const float*  __restrict__ P1g,
    const float*  __restrict__ f_cor,
    const float*  __restrict__ delta_p,
    float* __restrict__ out,
    float2* __restrict__ ws)
{
  __shared__ float4 S4[SH][SW4P];       // (u,v,T,q), 26.9 KB
  __shared__ float4 d1S[EH][EW4P];      // (d1u,d1v,d1T,d1q), 21.3 KB

  const int tid = threadIdx.x;
  const int tx = tid % NCOL;            // thread col (owns 4 outputs)
  const int ty = tid / NCOL;            // thread row 0..31
  const int w0 = blockIdx.x * TW;
  const int h0 = blockIdx.y * TH;
  const int k  = blockIdx.z;

  // ---- stage (u,v,T,q) as float4 with +-4 halo (clip lat, wrap lon) ----
  for (int idx = tid; idx < SH * SW4; idx += NTHR) {
    int rr = idx / SW4, cc = idx - rr * SW4;
    int pr = clipH(h0 + rr - 4);
    int pc = w0 + cc - 4;
    pc = pc < 0 ? pc + Ww : (pc >= Ww ? pc - Ww : pc);
    int g = (k * Hh + pr) * Ww + pc;
    float2 uvv = uv[g];
    S4[rr][cc] = make_float4(uvv.x, uvv.y, Tg[g], qg[g]);
  }
  __syncthreads();

  // ---- extended D1 of (u,v,T,q): 36 x 9 groups, ee-fastest lane map ----
  for (int idx = tid; idx < EH * (EW4 / 4); idx += NTHR) {
    int ee = idx % EH;                  // row fastest -> wave spans rows
    int gc = idx / EH;                  // 0..8
    int cb = gc * 4;
    int p = clipH(h0 + ee - 2);
    const float* Pr = P1g + p * PQROW;
    float4 a0 = {0,0,0,0}, a1 = {0,0,0,0}, a2 = {0,0,0,0}, a3 = {0,0,0,0};
    #pragma unroll
    for (int dl = 0; dl < 5; ++dl) {
      int sp = clipH(p + dl - 2);
      int rr = sp - h0 + 4;
      const float4* row = &S4[rr][cb];
      float4 g0 = row[0], g1 = row[1], g2 = row[2], g3 = row[3];
      float4 g4 = row[4], g5 = row[5], g6 = row[6], g7 = row[7];
      float4 wA = *(const float4*)(Pr + dl * 8);
      float wq0 = wA.x, wq1 = wA.y, wq2 = wA.z, wq3 = wA.w;
      float wq4 = Pr[dl * 8 + 4];
      ROWV(a0, g0, g1, g2, g3, g4);
      ROWV(a1, g1, g2, g3, g4, g5);
      ROWV(a2, g2, g3, g4, g5, g6);
      ROWV(a3, g3, g4, g5, g6, g7);
    }
    d1S[ee][cb + 0] = a0; d1S[ee][cb + 1] = a1;
    d1S[ee][cb + 2] = a2; d1S[ee][cb + 3] = a3;
  }
  __syncthreads();

  const int h = h0 + ty;
  const int hc = h < Hh ? h : (Hh - 1);
  const int wbase = w0 + tx * 4;
  const float f = f_cor[hc];
  const float invR = (float)(1.0 / 6371000.0);
  const float halfInvR = 0.5f * invR;
  const float cL = 200000.0f * invR * invR;
  const float* Pr1 = P1g + hc * PQROW;
  const float* Pr0 = P0g + hc * PQROW;

  // ---- second stencil: laplacians (d1S), D0(u) & D1(u^2+v^2) (S4) ----
  float4 lp0 = {0,0,0,0}, lp1 = {0,0,0,0}, lp2 = {0,0,0,0}, lp3 = {0,0,0,0};
  float du0 = 0.f, du1 = 0.f, du2 = 0.f, du3 = 0.f;   // D0(u)
  float dk0 = 0.f, dk1 = 0.f, dk2 = 0.f, dk3 = 0.f;   // D1(u^2+v^2)
  #pragma unroll
  for (int dl = 0; dl < 5; ++dl) {
    int sp = clipH(hc + dl - 2);
    int er = sp - h0 + 2;               // d1S row
    int rr = er + 2;                    // S4 row
    float4 wA = *(const float4*)(Pr1 + dl * 8);
    float wq0 = wA.x, wq1 = wA.y, wq2 = wA.z, wq3 = wA.w;
    float wq4 = Pr1[dl * 8 + 4];
    {
      const float4* row = &d1S[er][tx * 4];
      float4 g0 = row[0], g1 = row[1], g2 = row[2], g3 = row[3];
      float4 g4 = row[4], g5 = row[5], g6 = row[6], g7 = row[7];
      ROWV(lp0, g0, g1, g2, g3, g4);
      ROWV(lp1, g1, g2, g3, g4, g5);
      ROWV(lp2, g2, g3, g4, g5, g6);
      ROWV(lp3, g3, g4, g5, g6, g7);
    }
    {
      const float4* srow = &S4[rr][tx * 4 + 2];
      float4 s0 = srow[0], s1 = srow[1], s2 = srow[2], s3 = srow[3];
      float4 s4 = srow[4], s5 = srow[5], s6 = srow[6], s7 = srow[7];
      float k0 = fmaf(s0.y, s0.y, s0.x * s0.x);
      float k1 = fmaf(s1.y, s1.y, s1.x * s1.x);
      float k2 = fmaf(s2.y, s2.y, s2.x * s2.x);
      float k3 = fmaf(s3.y, s3.y, s3.x * s3.x);
      float k4 = fmaf(s4.y, s4.y, s4.x * s4.x);
      float k5 = fmaf(s5.y, s5.y, s5.x * s5.x);
      float k6 = fmaf(s6.y, s6.y, s6.x * s6.x);
      float k7 = fmaf(s7.y, s7.y, s7.x * s7.x);
      ROW5S(dk0, wq0, wq1, wq2, wq3, wq4, k0, k1, k2, k3, k4);
      ROW5S(dk1, wq0, wq1, wq2, wq3, wq4, k1, k2, k3, k4, k5);
      ROW5S(dk2, wq0, wq1, wq2, wq3, wq4, k2, k3, k4, k5, k6);
      ROW5S(dk3, wq0, wq1, wq2, wq3, wq4, k3, k4, k5, k6, k7);
      float4 w0A = *(const float4*)(Pr0 + dl * 8);
      float q0 = w0A.x, q1 = w0A.y, q2 = w0A.z, q3 = w0A.w;
      float q4 = Pr0[dl * 8 + 4];
      ROW5S(du0, q0, q1, q2, q3, q4, s0.x, s1.x, s2.x, s3.x, s4.x);
      ROW5S(du1, q0, q1, q2, q3, q4, s1.x, s2.x, s3.x, s4.x, s5.x);
      ROW5S(du2, q0, q1, q2, q3, q4, s2.x, s3.x, s4.x, s5.x, s6.x);
      ROW5S(du3, q0, q1, q2, q3, q4, s3.x, s4.x, s5.x, s6.x, s7.x);
    }
  }

  if (h < Hh && wbase < Ww) {
    const float dpk = delta_p[k];
    float4 duvA, duvB, dTv, dqv, wsA, wsB;
    {
      float4 d1c = d1S[ty + 2][tx * 4 + 2];
      float4 ctr = S4[ty + 4][tx * 4 + 4];
      float coef1 = fmaf(du0, invR, -f);
      duvA.x = fmaf(-coef1, ctr.y, cL * lp0.x);
      duvA.y = fmaf(coef1, ctr.x, -halfInvR * dk0) + cL * lp0.y;
      dTv.x = -(invR * d1c.z) * ctr.y + cL * lp0.z;
      dqv.x = fmaf(-(invR * d1c.w), ctr.y, cL * lp0.w);
      wsA.x = invR * d1c.y * dpk; wsA.y = d1c.z;
    }
    {
      float4 d1c = d1S[ty + 2][tx * 4 + 3];
      float4 ctr = S4[ty + 4][tx * 4 + 5];
      float coef1 = fmaf(du1, invR, -f);
      duvA.z = fmaf(-coef1, ctr.y, cL * lp1.x);
      duvA.w = fmaf(coef1, ctr.x, -halfInvR * dk1) + cL * lp1.y;
      dTv.y = -(invR * d1c.z) * ctr.y + cL * lp1.z;
      dqv.y = fmaf(-(invR * d1c.w), ctr.y, cL * lp1.w);
      wsA.z = invR * d1c.y * dpk; wsA.w = d1c.z;
    }
    {
      float4 d1c = d1S[ty + 2][tx * 4 + 4];
      float4 ctr = S4[ty + 4][tx * 4 + 6];
      float coef1 = fmaf(du2, invR, -f);
      duvB.x = fmaf(-coef1, ctr.y, cL * lp2.x);
      duvB.y = fmaf(coef1, ctr.x, -halfInvR * dk2) + cL * lp2.y;
      dTv.z = -(invR * d1c.z) * ctr.y + cL * lp2.z;
      dqv.z = fmaf(-(invR * d1c.w), ctr.y, cL * lp2.w);
      wsB.x = invR * d1c.y * dpk; wsB.y = d1c.z;
    }
    {
      float4 d1c = d1S[ty + 2][tx * 4 + 5];
      float4 ctr = S4[ty + 4][tx * 4 + 7];
      float coef1 = fmaf(du3, invR, -f);
      duvB.z = fmaf(-coef1, ctr.y, cL * lp3.x);
      duvB.w = fmaf(coef1, ctr.x, -halfInvR * dk3) + cL * lp3.y;
      dTv.w = -(invR * d1c.z) * ctr.y + cL * lp3.z;
      dqv.w = fmaf(-(invR * d1c.w), ctr.y, cL * lp3.w);
      wsB.z = invR * d1c.y * dpk; wsB.w = d1c.z;
    }
    const int gidx = (k * Hh + h) * Ww + wbase;
    float4* o4 = (float4*)out;
    o4[gidx >> 1] = duvA;
    o4[(gidx >> 1) + 1] = duvB;
    *(float4*)&out[OFF_DT + gidx] = dTv;
    *(float4*)&out[OFF_DQ + gidx] = dqv;
    float4* w4 = (float4*)ws;
    w4[gidx >> 1] = wsA;
    w4[(gidx >> 1) + 1] = wsB;
  }
}

// ---------------------------------------------------------------- pass 2 ----
__global__ __launch_bounds__(256) void pe_pass2(
    const float* __restrict__ Tg,
    const float* __restrict__ p_levels,
    const float2* __restrict__ ws,
    float* __restrict__ out)
{
  int i4 = blockIdx.x * 256 + threadIdx.x;   // quad index (4 points/thread)
  if (i4 >= HW / 4) return;
  const float invR = (float)(1.0 / 6371000.0);
  const float RCP = (float)(287.0 / 1004.0);

  float pl[Kz];
  #pragma unroll
  for (int k = 0; k < Kz; ++k) pl[k] = p_levels[k];

  const float4* T4 = (const float4*)Tg;
  const float4* ws4 = (const float4*)ws;
  float4* o4 = (float4*)out;
  float4* dT4 = (float4*)(out + OFF_DT);

  float4 cum = {0,0,0,0}, sumT = {0,0,0,0};
  float4 Tm = {0,0,0,0}, Tc = T4[i4];

  #pragma unroll
  for (int k = 0; k < Kz; ++k) {
    float4 Tp = (k < Kz - 1) ? T4[(k + 1) * (HW / 4) + i4] : make_float4(0,0,0,0);
    float4 wa = ws4[k * (HW / 2) + 2 * i4];
    float4 wb = ws4[k * (HW / 2) + 2 * i4 + 1];
    float om0 = fmaf(0.5f, wa.x, cum.x); cum.x += wa.x;
    float om1 = fmaf(0.5f, wa.z, cum.y); cum.y += wa.z;
    float om2 = fmaf(0.5f, wb.x, cum.z); cum.z += wb.x;
    float om3 = fmaf(0.5f, wb.z, cum.w); cum.w += wb.z;

    float4 dTdp;
    if (k == 0) {
      float idp = 1.f / (pl[1] - pl[0]);
      dTdp.x = (Tp.x - Tc.x) * idp; dTdp.y = (Tp.y - Tc.y) * idp;
      dTdp.z = (Tp.z - Tc.z) * idp; dTdp.w = (Tp.w - Tc.w) * idp;
    } else if (k == Kz - 1) {
      float idp = 1.f / (pl[Kz - 1] - pl[Kz - 2]);
      dTdp.x = (Tc.x - Tm.x) * idp; dTdp.y = (Tc.y - Tm.y) * idp;
      dTdp.z = (Tc.z - Tm.z) * idp; dTdp.w = (Tc.w - Tm.w) * idp;
    } else {
      float idp = 1.f / (pl[k + 1] - pl[k - 1]);
      dTdp.x = (Tp.x - Tm.x) * idp; dTdp.y = (Tp.y - Tm.y) * idp;
      dTdp.z = (Tp.z - Tm.z) * idp; dTdp.w = (Tp.w - Tm.w) * idp;
    }
    float iplk = RCP / pl[k];
    float4 dt = dT4[k * (HW / 4) + i4];
    dt.x += om0 * fmaf(iplk, Tc.x, -dTdp.x);
    dt.y += om1 * fmaf(iplk, Tc.y, -dTdp.y);
    dt.z += om2 * fmaf(iplk, Tc.z, -dTdp.z);
    dt.w += om3 * fmaf(iplk, Tc.w, -dTdp.w);
    dT4[k * (HW / 4) + i4] = dt;

    float4 oa = o4[k * (HW / 2) + 2 * i4];
    float4 ob = o4[k * (HW / 2) + 2 * i4 + 1];
    oa.y += sumT.x; oa.w += sumT.y;
    ob.y += sumT.z; ob.w += sumT.w;
    o4[k * (HW / 2) + 2 * i4] = oa;
    o4[k * (HW / 2) + 2 * i4 + 1] = ob;

    if (k < Kz - 1) {
      float c = -287.0f * logf(pl[k] / pl[k + 1]) * invR;
      sumT.x = fmaf(c, wa.y, sumT.x);
      sumT.y = fmaf(c, wa.w, sumT.y);
      sumT.z = fmaf(c, wb.y, sumT.z);
      sumT.w = fmaf(c, wb.w, sumT.w);
    }
    Tm = Tc; Tc = Tp;
  }
}

// ------------------------------------------------- fallback fused kernel ----
constexpr int FTH = 16, FTW = 16;
constexpr int FSH = FTH + 8, FSW = FTW + 8;
constexpr int FEH = FTH + 4, FEW = FTW + 4;
constexpr int FSWp = FSW + 1, FEWp = FEW + 1;

__global__ __launch_bounds__(256) void pe_step(
    const float2* __restrict__ uv,
    const float*  __restrict__ Tg,
    const float*  __restrict__ qg,
    const float*  __restrict__ psi,
    const float*  __restrict__ quad,
    const float*  __restrict__ f_cor,
    const float*  __restrict__ p_levels,
    const float*  __restrict__ delta_p,
    float* __restrict__ out)
{
  __shared__ float uS[FSH][FSWp], vS[FSH][FSWp], TS[FSH][FSWp], qS[FSH][FSWp];
  __shared__ float keS[FEH][FEWp];
  __shared__ float d1uS[FEH][FEWp], d1vS[FEH][FEWp], d1TS[FEH][FEWp], d1qS[FEH][FEWp];
  __shared__ float P1L[FEH][25];
  __shared__ float P0L[FTH][25];
  __shared__ float quadA[FSH];
  __shared__ float pl[8], dps[8];

  const int tid = threadIdx.x;
  const int tx = tid & (FTW - 1);
  const int ty = tid >> 4;
  const int w0 = blockIdx.x * FTW;
  const int h0 = blockIdx.y * FTH;

  if (tid < FSH) quadA[tid] = quad[clipH(h0 + tid - 4)];
  if (tid < 8) { pl[tid] = p_levels[tid]; dps[tid] = delta_p[tid]; }
  for (int idx = tid; idx < FEH * 25; idx += 256) {
    int ee = idx / 25, t = idx - ee * 25;
    int p = clipH(h0 + ee - 2);
    float s = 0.f;
    #pragma unroll
    for (int kk = 0; kk < 5; ++kk)
      s += psi[kk * (2 * Hh * 25) + Hh * 25 + p * 25 + t];
    P1L[ee][t] = s;
  }
  for (int idx = tid; idx < FTH * 25; idx += 256) {
    int r = idx / 25, t = idx - r * 25;
    int p = clipH(h0 + r);
    float s = 0.f;
    #pragma unroll
    for (int kk = 0; kk < 5; ++kk)
      s += psi[kk * (2 * Hh * 25) + p * 25 + t];
    P0L[r][t] = s;
  }
  __syncthreads();

  const int h = h0 + ty;
  const bool act = h < Hh;
  const int hc = act ? h : (Hh - 1);
  const int w = w0 + tx;
  const float f = f_cor[hc];
  const float invR = (float)(1.0 / 6371000.0);
  const float cL = 200000.0f * invR * invR;
  const float RCP = (float)(287.0 / 1004.0);

  float cum = 0.f;
  float sumT = 0.f;

  #pragma unroll 1
  for (int k = 0; k < Kz; ++k) {
    __syncthreads();
    for (int idx = tid; idx < FSH * FSW; idx += 256) {
      int rr = idx / FSW, cc = idx - rr * FSW;
      int pr = clipH(h0 + rr - 4);
      int pc = w0 + cc - 4;
      pc = pc < 0 ? pc + Ww : (pc >= Ww ? pc - Ww : pc);
      int g = (k * Hh + pr) * Ww + pc;
      float2 uvv = uv[g];
      uS[rr][cc] = uvv.x; vS[rr][cc] = uvv.y;
      TS[rr][cc] = Tg[g]; qS[rr][cc] = qg[g];
    }
    __syncthreads();
    for (int idx = tid; idx < FEH * FEW; idx += 256) {
      int ee = idx / FEW, ec = idx - ee * FEW;
      float su = uS[ee + 2][ec + 2], sv = vS[ee + 2][ec + 2];
      keS[ee][ec] = 0.5f * (su * su + sv * sv);
    }
    for (int idx = tid; idx < FEH * FEW; idx += 256) {
      int ee = idx / FEW, ec = idx - ee * FEW;
      int p = clipH(h0 + ee - 2);
      float au = 0.f, av = 0.f, aT = 0.f, aq = 0.f;
      #pragma unroll
      for (int dl = 0; dl < 5; ++dl) {
        int sp = clipH(p + dl - 2);
        int rr = sp - h0 + 4;
        float qv = quadA[rr];
        float ru = 0.f, rv = 0.f, rT = 0.f, rq = 0.f;
        #pragma unroll
        for (int dw = 0; dw < 5; ++dw) {
          float wgt = P1L[ee][dl * 5 + dw];
          ru = fmaf(wgt, uS[rr][ec + dw], ru);
          rv = fmaf(wgt, vS[rr][ec + dw], rv);
          rT = fmaf(wgt, TS[rr][ec + dw], rT);
          rq = fmaf(wgt, qS[rr][ec + dw], rq);
        }
        au = fmaf(qv, ru, au); av = fmaf(qv, rv, av);
        aT = fmaf(qv, rT, aT); aq = fmaf(qv, rq, aq);
      }
      d1uS[ee][ec] = au; d1vS[ee][ec] = av;
      d1TS[ee][ec] = aT; d1qS[ee][ec] = aq;
    }
    __syncthreads();

    float d0u = 0.f, d1ke = 0.f;
    #pragma unroll
    for (int dl = 0; dl < 5; ++dl) {
      int sp = clipH(hc + dl - 2);
      int rr = sp - h0 + 4;
      int er = sp - h0 + 2;
      float qv = quadA[rr];
      float r0 = 0.f, rk = 0.f;
      #pragma unroll
      for (int dw = 0; dw < 5; ++dw) {
        r0 = fmaf(P0L[ty][dl * 5 + dw], uS[rr][tx + 2 + dw], r0);
        rk = fmaf(P1L[ty + 2][dl * 5 + dw], keS[er][tx + dw], rk);
      }
      d0u = fmaf(qv, r0, d0u);
      d1ke = fmaf(qv, rk, d1ke);
    }

    float lapu = 0.f, lapv = 0.f, lapT = 0.f, lapq = 0.f;
    #pragma unroll
    for (int dl = 0; dl < 5; ++dl) {
      int sp = clipH(hc + dl - 2);
      int er = sp - h0 + 2;
      float qv = quadA[er + 2];
      float ru = 0.f, rv = 0.f, rT = 0.f, rq = 0.f;
      #pragma unroll
      for (int dw = 0; dw < 5; ++dw) {
        float wgt = P1L[ty + 2][dl * 5 + dw];
        ru = fmaf(wgt, d1uS[er][tx + dw], ru);
        rv = fmaf(wgt, d1vS[er][tx + dw], rv);
        rT = fmaf(wgt, d1TS[er][tx + dw], rT);
        rq = fmaf(wgt, d1qS[er][tx + dw], rq);
      }
      lapu = fmaf(qv, ru, lapu); lapv = fmaf(qv, rv, lapv);
      lapT = fmaf(qv, rT, lapT); lapq = fmaf(qv, rq, lapq);
    }

    float d1T_c = d1TS[ty + 2][tx + 2];
    float d1v_c = d1vS[ty + 2][tx + 2];
    float d1q_c = d1qS[ty + 2][tx + 2];
    float uc = uS[ty + 4][tx + 4], vc = vS[ty + 4][tx + 4];
    float Tc = TS[ty + 4][tx + 4];

    float coef1 = fmaf(d0u, invR, -f);
    float duv0 = fmaf(-coef1, vc, cL * lapu);
    float yv1 = fmaf(-invR, d1ke, sumT);
    float duv1 = fmaf(coef1, uc, yv1) + cL * lapv;

    float div = invR * d1v_c;
    float dpk = dps[k];
    float omega = fmaf(0.5f * div, dpk, cum);
    cum = fmaf(div, dpk, cum);

    int gidx = (k * Hh + hc) * Ww + w;
    float dTdp;
    if (k == 0) {
      float Tp = Tg[gidx + HW];
      dTdp = (Tp - Tc) / (pl[1] - pl[0]);
    } else if (k == Kz - 1) {
      float Tm = Tg[gidx - HW];
      dTdp = (Tc - Tm) / (pl[Kz - 1] - pl[Kz - 2]);
    } else {
      float Tp = Tg[gidx + HW];
      float Tm = Tg[gidx - HW];
      dTdp = (Tp - Tm) / (pl[k + 1] - pl[k - 1]);
    }
    float adv = -(invR * d1T_c) * vc;
    float dT = adv + omega * ((RCP * Tc) / pl[k] - dTdp) + cL * lapT;
    float dq = fmaf(-(invR * d1q_c), vc, cL * lapq);

    if (act) {
      ((float2*)out)[(k * Hh + h) * Ww + w] = make_float2(duv0, duv1);
      out[OFF_DT + gidx] = dT;
      out[OFF_DQ + gidx] = dq;
    }

    if (k < Kz - 1) {
      float lpr = logf(pl[k] / pl[k + 1]);
      float wTk = (float)(-287.0 * (double)lpr / 6371000.0);
      sumT = fmaf(wTk, d1T_c, sumT);
    }
  }
}

extern "C" void kernel_launch(void* const* d_in, const int* in_sizes, int n_in,
                              void* d_out, int out_size, void* d_ws, size_t ws_size,
                              hipStream_t stream) {
  (void)in_sizes; (void)n_in; (void)out_size;
  const float2* uv   = (const float2*)d_in[0];
  const float*  T    = (const float*) d_in[1];
  const float*  q    = (const float*) d_in[2];
  const float*  psi  = (const float*) d_in[3];
  const float*  quad = (const float*) d_in[4];
  const float*  fc   = (const float*) d_in[5];
  const float*  pl   = (const float*) d_in[6];
  const float*  dp   = (const float*) d_in[7];

  const size_t ws_div_floats = (size_t)2 * Kz * HW;        // K*HW float2
  const size_t pq_floats = (size_t)Hh * PQROW;             // 14440
  const size_t ws_need = (ws_div_floats + 2 * pq_floats) * sizeof(float);
  if (ws_size >= ws_need) {
    float* wsF = (float*)d_ws;
    float* P0g = wsF + ws_div_floats;
    float* P1g = P0g + pq_floats;

    dim3 gt1((Hh * PQROW + 255) / 256);                    // 57 blocks
    hipLaunchKernelGGL(pe_tab_pq, gt1, dim3(256), 0, stream, psi, quad, P0g, P1g);

    dim3 g1(GX, GY, Kz);                                   // 23 x 12 x 8
    hipLaunchKernelGGL(pe_pass1, g1, dim3(NTHR), 0, stream,
                       uv, T, q, P0g, P1g, fc, dp, (float*)d_out, (float2*)d_ws);

    dim3 g2((HW / 4 + 255) / 256);
    hipLaunchKernelGGL(pe_pass2, g2, dim3(256), 0, stream,
                       T, pl, (const float2*)d_ws, (float*)d_out);
  } else {
    dim3 grid(Ww / FTW, (Hh + FTH - 1) / FTH);
    hipLaunchKernelGGL(pe_step, grid, dim3(256), 0, stream,
                       uv, T, q, psi, quad, fc, pl, dp, (float*)d_out);
  }
}